// Round 6
// baseline (307.216 us; speedup 1.0000x reference)
//
#include <hip/hip_runtime.h>
#include <hip/hip_bf16.h>

#define B_    4
#define NQ    512
#define NKV   2048
#define NT    2560     // NKV + NQ
#define DIM_  1024
#define HEADS 16
#define DH    64
#define NSEQT 10240    // B_*NT
// SCALE * log2(e): attention uses raw exp2
#define SCALE_Q_L2E 0.18033688011112042f

typedef short bf16x8 __attribute__((ext_vector_type(8)));
typedef float f32x4  __attribute__((ext_vector_type(4)));
typedef __hip_bfloat16 bf16;

// async global->LDS, 16B per lane. Global side may be a per-lane gather;
// LDS side is wave-uniform base + lane*16.
__device__ inline void gll16(const bf16* g, bf16* l) {
  __builtin_amdgcn_global_load_lds(
      (const __attribute__((address_space(1))) unsigned int*)g,
      (__attribute__((address_space(3))) unsigned int*)l, 16, 0, 0);
}

#define VMCNT(n) asm volatile("s_waitcnt vmcnt(" #n ")" ::: "memory")
#define BAR() __builtin_amdgcn_s_barrier()

// ---------------------------------------------- fused LayerNorm + weight^T
// blocks [0, 2560): LN, one WAVE per row (4 rows/block, no syncthreads).
// blocks [2560, 3584): 4x trw 64x64 weight transpose tiles.
__global__ __launch_bounds__(256) void prep2_kernel(
    const float* __restrict__ query, const float* __restrict__ kv,
    const float* __restrict__ lgq, const float* __restrict__ lbq,
    const float* __restrict__ lgkv, const float* __restrict__ lbkv,
    bf16* __restrict__ X,
    const float* __restrict__ W0, const float* __restrict__ W1,
    const float* __restrict__ W2, const float* __restrict__ W3,
    bf16* __restrict__ T0, bf16* __restrict__ T1,
    bf16* __restrict__ T2, bf16* __restrict__ T3)
{
  __shared__ __align__(16) char psm[9216];
  const int t = threadIdx.x;
  const int blkid = blockIdx.x;
  if (blkid < 2560) {
    const int w = t>>6, l = t&63;
    const int R = blkid*4 + w;                 // global row in X
    int b = R / NT, r = R % NT;
    const float *src, *gp, *bp;
    if (r < NKV) { src = kv    + ((size_t)b*NKV + r)*DIM_;      gp = lgkv; bp = lbkv; }
    else         { src = query + ((size_t)b*NQ + (r-NKV))*DIM_; gp = lgq;  bp = lbq;  }
    float4 v[4];
    #pragma unroll
    for (int j=0;j<4;++j) v[j] = ((const float4*)src)[j*64 + l];
    float s = 0.f, s2 = 0.f;
    #pragma unroll
    for (int j=0;j<4;++j){
      s  += v[j].x+v[j].y+v[j].z+v[j].w;
      s2 += v[j].x*v[j].x+v[j].y*v[j].y+v[j].z*v[j].z+v[j].w*v[j].w;
    }
    #pragma unroll
    for (int m=1;m<64;m<<=1){ s += __shfl_xor(s,m,64); s2 += __shfl_xor(s2,m,64); }
    float mu = s*(1.0f/DIM_);
    float rs = rsqrtf(s2*(1.0f/DIM_) - mu*mu + 1e-5f);
    uint2* drow = (uint2*)(X + (size_t)R*DIM_);
    #pragma unroll
    for (int j=0;j<4;++j){
      float4 gg = ((const float4*)gp)[j*64 + l];
      float4 b4 = ((const float4*)bp)[j*64 + l];
      union { unsigned int u[2]; bf16 h[4]; } pk;
      pk.h[0] = __float2bfloat16((v[j].x-mu)*rs*gg.x + b4.x);
      pk.h[1] = __float2bfloat16((v[j].y-mu)*rs*gg.y + b4.y);
      pk.h[2] = __float2bfloat16((v[j].z-mu)*rs*gg.z + b4.z);
      pk.h[3] = __float2bfloat16((v[j].w-mu)*rs*gg.w + b4.w);
      drow[j*64 + l] = make_uint2(pk.u[0], pk.u[1]);
    }
  } else {
    int l = blkid - 2560;
    const float* W; bf16* Wt;
    switch (l>>8) {
      case 0: W=W0; Wt=T0; break;
      case 1: W=W1; Wt=T1; break;
      case 2: W=W2; Wt=T2; break;
      default: W=W3; Wt=T3; break;
    }
    int rem = l & 255;
    int k0 = (rem&15)*64, n0 = (rem>>4)*64;
    bf16* Ws = (bf16*)psm;            // 64 x 72
    int kr = t>>2, nseg = (t&3)*16;
    const float4* s4 = (const float4*)(W + (size_t)(k0+kr)*DIM_ + n0 + nseg);
    union { uint4 u[2]; bf16 h[16]; } pk;
    #pragma unroll
    for (int j=0;j<4;j++){
      float4 v = s4[j];
      pk.h[j*4+0]=__float2bfloat16(v.x); pk.h[j*4+1]=__float2bfloat16(v.y);
      pk.h[j*4+2]=__float2bfloat16(v.z); pk.h[j*4+3]=__float2bfloat16(v.w);
    }
    *(uint4*)(Ws + kr*72 + nseg)     = pk.u[0];
    *(uint4*)(Ws + kr*72 + nseg + 8) = pk.u[1];
    __syncthreads();
    int n = t&63, kseg = t>>6;
    union { uint4 u[2]; bf16 h[16]; } o;
    #pragma unroll
    for (int k=0;k<16;k++) o.h[k] = Ws[(kseg*16+k)*72 + n];
    bf16* dst = Wt + (size_t)(n0+n)*DIM_ + k0 + kseg*16;
    *(uint4*)dst = o.u[0];
    *(uint4*)(dst+8) = o.u[1];
  }
}

// ------------------------------------------------------------- GEMM core v4
// 128x128 tile, BK=64, 4 waves (2x2). A: double-buffered LDS (32 KiB) via
// gll16 + granule-XOR swizzle (conflict-free). B: DIRECT global->VGPR frags
// (no LDS round-trip; halves LDS traffic -> LDS pipe ~= MFMA pipe), double
// register bank bA/bB prefetched one tile ahead; B loads stay in flight
// across the barrier (counted VMCNT(8) retires only the 4 A stages).
// Order pinned: A gll16 first, sched_barrier(0), then B loads, so vmcnt
// accounting holds (global reads may otherwise hoist past LDS-writing ops).
__device__ __forceinline__ void gemm_core4(
    const bf16* __restrict__ A, const bf16* __restrict__ Bmat,
    const float* __restrict__ bias, const float* __restrict__ residual,
    void* __restrict__ outv, int rows_per_batch, int row_offset,
    int a_batch_stride_rows, int n_seq, float scale,
    int emode, int m0, int n0, char* smem)
{
  char* const sA = smem;             // 2 x 16384 A dbuf
  float* Ts = (float*)smem;          // epilogue: 32 rows x stride 132

  const int t = threadIdx.x;
  const int srow = t >> 3;                 // 0..31: row within 32-row chunk
  const int gsw  = (t & 7) ^ (srow & 7);   // pre-swizzled source granule
  const bf16* pA[4];
  #pragma unroll
  for (int c = 0; c < 4; ++c) {
    int gm = m0 + c*32 + srow;
    int bi = gm / rows_per_batch;
    pA[c] = A + ((size_t)bi*a_batch_stride_rows + row_offset
                 + (gm - bi*rows_per_batch))*(size_t)DIM_ + gsw*8;
  }
  const int toff = t*16;

  const int wave = t>>6, lane = t&63, qq = lane>>4, mr = lane&15;
  const int wm = (wave>>1)*64, wn = (wave&1)*64;
  const int xq0 = (( qq    ) ^ (mr&7)) << 4;
  const int xq1 = ((4 + qq ) ^ (mr&7)) << 4;

  // B fragment row pointers (direct loads, no swizzle needed)
  const bf16* pB[4];
  #pragma unroll
  for (int ns = 0; ns < 4; ++ns)
    pB[ns] = Bmat + (size_t)(n0 + wn + ns*16 + mr)*(size_t)DIM_ + qq*8;

  f32x4 acc[4][4] = {};
  bf16x8 bA[4][2], bB[4][2];

  // prologue: A(t0)->buf0; B(t0)->bA; full drain once
  #pragma unroll
  for (int c=0;c<4;++c) gll16(pA[c], (bf16*)(sA + c*4096 + toff));
  __builtin_amdgcn_sched_barrier(0);
  #pragma unroll
  for (int ns=0;ns<4;++ns)
    #pragma unroll
    for (int kh=0;kh<2;++kh)
      bA[ns][kh] = *(const bf16x8*)(pB[ns] + kh*32);
  VMCNT(0);
  BAR();

#define GBODY(CB, NB, KON, BCUR, BNXT)                                         \
  {                                                                            \
    _Pragma("unroll")                                                          \
    for (int c=0;c<4;++c) gll16(pA[c]+(KON), (bf16*)(sA + (NB) + c*4096 + toff)); \
    __builtin_amdgcn_sched_barrier(0);                                         \
    _Pragma("unroll")                                                          \
    for (int ns=0;ns<4;++ns)                                                   \
      _Pragma("unroll")                                                        \
      for (int kh=0;kh<2;++kh)                                                 \
        BNXT[ns][kh] = *(const bf16x8*)(pB[ns] + (KON) + kh*32);               \
    _Pragma("unroll")                                                          \
    for (int kh=0;kh<2;++kh){                                                  \
      const int xq = kh ? xq1 : xq0;                                           \
      bf16x8 af[4];                                                            \
      _Pragma("unroll")                                                        \
      for (int ms=0; ms<4; ++ms)                                               \
        af[ms] = *(const bf16x8*)(sA + (CB) + (wm + ms*16 + mr)*128 + xq);     \
      __builtin_amdgcn_s_setprio(1);                                           \
      _Pragma("unroll")                                                        \
      for (int ms=0; ms<4; ++ms)                                               \
        _Pragma("unroll")                                                      \
        for (int ns=0; ns<4; ++ns)                                             \
          acc[ms][ns] = __builtin_amdgcn_mfma_f32_16x16x32_bf16(               \
              af[ms], BCUR[ns][kh], acc[ms][ns], 0,0,0);                       \
      __builtin_amdgcn_s_setprio(0);                                           \
    }                                                                          \
    VMCNT(8);  /* A(t+1) landed; 8 B(t+1) loads stay in flight */              \
    BAR();                                                                     \
  }

  for (int kt2 = 0; kt2 < 16; kt2 += 2) {
    const int ko1 = (kt2+1)*64;                          // always < 16*64
    const int ko2 = ((kt2+2 < 16) ? kt2+2 : 15)*64;      // clamp: junk restage
    GBODY(0,     16384, ko1, bA, bB);
    GBODY(16384, 0,     ko2, bB, bA);
  }
#undef GBODY

  VMCNT(0);       // drain clamped junk restages
  __syncthreads();

  // epilogue: 4 rounds of 32 rows through LDS
  const int lr = t>>3, cs = (t&7)*16;
  for (int R=0; R<4; R++){
    if ((wave>>1) == (R>>1)) {
      #pragma unroll
      for (int ms2=0; ms2<2; ms2++){
        int ms = (R&1)*2 + ms2;
        #pragma unroll
        for (int ns=0; ns<4; ns++){
          int col = wn + ns*16 + mr;
          #pragma unroll
          for (int r=0;r<4;r++)
            Ts[(ms2*16 + qq*4 + r)*132 + col] = acc[ms][ns][r];
        }
      }
    }
    __syncthreads();
    float v[16];
    #pragma unroll
    for (int j=0;j<4;j++){
      float4 f = *(const float4*)(Ts + lr*132 + cs + j*4);
      v[j*4+0]=f.x; v[j*4+1]=f.y; v[j*4+2]=f.z; v[j*4+3]=f.w;
    }
    int gr = m0 + R*32 + lr;
    int gc = n0 + cs;
    if (emode == 0) {
      float* out = (float*)outv;
      size_t base = (size_t)gr*DIM_ + gc;
      #pragma unroll
      for (int j=0;j<4;j++){
        float4 bv = *(const float4*)(bias + gc + j*4);
        float4 rv = *(const float4*)(residual + base + j*4);
        float4 o4;
        o4.x = v[j*4+0] + bv.x + rv.x;
        o4.y = v[j*4+1] + bv.y + rv.y;
        o4.z = v[j*4+2] + bv.z + rv.z;
        o4.w = v[j*4+3] + bv.w + rv.w;
        *(float4*)(out + base + j*4) = o4;
      }
    } else if (emode == 1) {
      int bb = gr / rows_per_batch;
      int n  = gr - bb*rows_per_batch;
      int hh = gc>>6, dh = gc&63;
      bf16* out = (bf16*)outv + ((size_t)(bb*HEADS + hh)*n_seq + n)*DH + dh;
      union { uint4 u[2]; bf16 h[16]; } pk;
      #pragma unroll
      for (int j=0;j<16;j++) pk.h[j] = __float2bfloat16((v[j] + bias[gc+j])*scale);
      *(uint4*)out     = pk.u[0];
      *(uint4*)(out+8) = pk.u[1];
    } else {
      float bc = bias[gr];
      bf16* out = (bf16*)outv + (size_t)gr*NSEQT + gc;
      union { uint4 u[2]; bf16 h[16]; } pk;
      #pragma unroll
      for (int j=0;j<16;j++) pk.h[j] = __float2bfloat16(v[j] + bc);
      *(uint4*)out     = pk.u[0];
      *(uint4*)(out+8) = pk.u[1];
    }
    __syncthreads();
  }
}

// -------------------------------------------- fused Q/K/V projection GEMMs
// blocks [0,128): Q. [128,768): K (m fastest; same-m n-blocks are 80 apart
// = 0 mod 8 -> same XCD -> A-panel L2 reuse). [768,1408): V^T (n fastest,
// same property for the X panels on the B side).
__global__ __launch_bounds__(256) void gemm_qkv5(
    const bf16* __restrict__ X,
    const bf16* __restrict__ WtQ, const bf16* __restrict__ WtK,
    const bf16* __restrict__ WtV,
    const float* __restrict__ bq, const float* __restrict__ bk,
    const float* __restrict__ bv,
    bf16* __restrict__ Qhb, bf16* __restrict__ Khb, bf16* __restrict__ VTg)
{
  __shared__ __align__(16) char smem[32768];
  const int blk = blockIdx.x;
  if (blk < 128) {
    gemm_core4(X, WtQ, bq, nullptr, Qhb, NQ, NKV, NT, NQ, SCALE_Q_L2E, 1,
               (blk&15)*128, (blk>>4)*128, smem);
  } else if (blk < 768) {
    int l = blk - 128;
    gemm_core4(X, WtK, bk, nullptr, Khb, NT, 0, NT, NT, 1.0f, 1,
               (l%80)*128, (l/80)*128, smem);
  } else {
    int l = blk - 768;
    gemm_core4(WtV, X, bv, nullptr, VTg, DIM_, 0, DIM_, NSEQT, 1.0f, 2,
               (l/80)*128, (l%80)*128, smem);
  }
}

// ------------------------------------------------ output projection GEMM
__global__ __launch_bounds__(256) void gemm_o(
    const bf16* __restrict__ Ctx, const bf16* __restrict__ WtO,
    const float* __restrict__ bo, const float* __restrict__ residual,
    float* __restrict__ out)
{
  __shared__ __align__(16) char smem[32768];
  const int blk = blockIdx.x;
  gemm_core4(Ctx, WtO, bo, residual, out, B_*NQ, 0, B_*NQ, NQ, 1.0f, 0,
             (blk&15)*128, (blk>>4)*128, smem);
}

// --------------------------------------------------------------- Attention
// attn6 (round-3 proven): block = 64 q-rows of one (b,h). Wave w: q-rows
// (w>>1)*32..+31, key half (w&1)*32 of each 64-key tile. K staged
// key-interleaved; packed-pair P words; cross-pair O/l merge via LDS.
__global__ __launch_bounds__(256) void attn6_kernel(
    const bf16* __restrict__ Qh, const bf16* __restrict__ Kh,
    const bf16* __restrict__ VTg, bf16* __restrict__ Ctx)
{
  __shared__ __align__(16) bf16 KV[2][8192];          // 32 KB (2 buffers)
  __shared__ __align__(16) unsigned int Ps[4][640];   // per-wave P: 32 rows x 20 words

  const int t = threadIdx.x, wave = t>>6, lane = t&63;
  const int qq = lane>>4, mr = lane&15;
  const int blk = blockIdx.x;
  const int bh = (blk&7)*8 + (blk>>6);      // same bh -> same blk%8 slot (XCD)
  const int q0 = ((blk>>3)&7)*64;
  const int b = bh>>4, h = bh&15;
  const int pair = wave>>1, kh = wave&1;
  const int qb = pair*32;

  const int sl = t>>2, sc = t&3;
  const int skey = 32*(sl>>5) + 2*(sl&15) + ((sl>>4)&1);
  const bf16* Kb  = Kh + (size_t)bh*NT*DH + (size_t)skey*DH + sc*8;
  const bf16* VbT = VTg + ((size_t)(h*DH) + sl)*NSEQT + (size_t)b*NT + sc*8;

  // Q fragments for this wave's 32 q-rows (two 16-row subtiles)
  bf16x8 qf[2][2];
  #pragma unroll
  for (int mt=0; mt<2; mt++){
    const bf16* Qb = Qh + ((size_t)bh*NQ + q0 + qb + mt*16 + mr)*DH;
    qf[mt][0] = *(const bf16x8*)(Qb + qq*8);
    qf[mt][1] = *(const bf16x8*)(Qb + 32 + qq*8);
  }

  f32x4 o[2][4] = {};
  float l[2][4] = {};
  unsigned int* Pw = &Ps[wave][0];

  // prefetch tile 0 into buffer 0
  {
    bf16* bp = &KV[0][0];
    gll16(Kb,        bp + t*8);
    gll16(Kb + 32,   bp + 2048 + t*8);
    gll16(VbT,       bp + 4096 + t*8);
    gll16(VbT + 32,  bp + 6144 + t*8);
  }

  for (int it = 0; it < NT/64; it++) {
    __syncthreads();
    if (it + 1 < NT/64) {
      int kt = (it+1)*64;
      bf16* bp = &KV[(it+1)&1][0];
      gll16(Kb  + (size_t)kt*DH,      bp + t*8);
      gll16(Kb  + (size_t)kt*DH + 32, bp + 2048 + t*8);
      gll16(VbT + kt,                 bp + 4096 + t*8);
      gll16(VbT + kt + 32,            bp + 6144 + t*8);
    }
    const bf16* cbuf = &KV[it&1][0];

    // K fragments: this wave's key half, 2 subtiles of 16 keys
    bf16x8 kf[2][2];
    #pragma unroll
    for (int g=0; g<2; g++){
      kf[g][0] = *(const bf16x8*)(cbuf + (32*kh + 16*g + mr)*32 + qq*8);
      kf[g][1] = *(const bf16x8*)(cbuf + 2048 + (32*kh + 16*g + mr)*32 + qq*8);
    }
    f32x4 s[2][2];
    #pragma unroll
    for (int mt=0; mt<2; mt++)
      #pragma unroll
      for (int g=0; g<2; g++){
        f32x4 z = {};
        z = __builtin_amdgcn_mfma_f32_16x16x32_bf16(qf[mt][0], kf[g][0], z, 0,0,0);
        z = __builtin_amdgcn_mfma_f32_16x16x32_bf16(qf[mt][1], kf[g][1], z, 0,0,0);
        s[mt][g] = z;
      }
    // V fragments: this wave's key-half panel
    bf16x8 vf[4];
    #pragma unroll
    for (int n2=0; n2<4; n2++)
      vf[n2] = *(const bf16x8*)(cbuf + 4096 + kh*2048 + (n2*16+mr)*32 + qq*8);

    // exp2 + pack pair (keys 2mr, 2mr+1 of the half) -> one word per q-row
    #pragma unroll
    for (int mt=0; mt<2; mt++)
      #pragma unroll
      for (int r=0; r<4; r++){
        float e0 = __builtin_amdgcn_exp2f(s[mt][0][r]);
        float e1 = __builtin_amdgcn_exp2f(s[mt][1][r]);
        l[mt][r] += e0 + e1;
        unsigned a0 = __float_as_uint(e0) + 0x8000u;
        unsigned a1 = __float_as_uint(e1) + 0x8000u;
        Pw[(mt*16 + qq*4 + r)*20 + mr] = __builtin_amdgcn_perm(a1, a0, 0x07060302u);
      }
    asm volatile("s_waitcnt lgkmcnt(0)" ::: "memory");
    bf16x8 pa[2];
    #pragma unroll
    for (int mt=0; mt<2; mt++)
      pa[mt] = *(const bf16x8*)(Pw + (mt*16+mr)*20 + qq*4);
    #pragma unroll
    for (int mt=0; mt<2; mt++)
      #pragma unroll
      for (int n2=0; n2<4; n2++)
        o[mt][n2] = __builtin_amdgcn_mfma_f32_16x16x32_bf16(pa[mt], vf[n2], o[mt][n2], 0,0,0);
  }

  // partial row sums over this wave's key half
  float lsum[2][4];
  #pragma unroll
  for (int mt=0; mt<2; mt++)
    #pragma unroll
    for (int r=0; r<4; r++){
      float v = l[mt][r];
      #pragma unroll
      for (int m=1;m<16;m<<=1) v += __shfl_xor(v, m, 16);
      lsum[mt][r] = v;
    }

  // cross-pair merge via LDS (waves kh=1 publish, kh=0 merge+normalize)
  __syncthreads();
  float* Of  = (float*)&KV[0][0];   // 64 rows x stride 68 f32 (17408 B)
  float* lsh = (float*)&Ps[0][0];   // 64 f32
  if (kh == 1) {
    #pragma unroll
    for (int mt=0; mt<2; mt++){
      #pragma unroll
      for (int n2=0; n2<4; n2++)
        #pragma unroll
        for (int r=0; r<4; r++)
          Of[(qb + mt*16 + qq*4 + r)*68 + n2*16 + mr] = o[mt][n2][r];
      if (mr == 0)
        #pragma unroll
        for (int r=0; r<4; r++)
          lsh[qb + mt*16 + qq*4 + r] = lsum[mt][r];
    }
  }
  __syncthreads();
  if (kh == 0) {
    #pragma unroll
    for (int mt=0; mt<2; mt++)
      #pragma unroll
      for (int r=0; r<4; r++){
        int row = qb + mt*16 + qq*4 + r;
        float rl = 1.0f / (lsum[mt][r] + lsh[row]);
        #pragma unroll
        for (int n2=0; n2<4; n2++){
          int idx = row*68 + n2*16 + mr;
          Of[idx] = (o[mt][n2][r] + Of[idx]) * rl;
        }
      }
  }
  __syncthreads();
  // vectorized store: each thread writes 16 bf16 of one row
  {
    int row = t>>2, seg = (t&3)*16;
    union { uint4 u[2]; bf16 hh[16]; } pkv;
    #pragma unroll
    for (int j=0;j<16;j++) pkv.hh[j] = __float2bfloat16(Of[row*68 + seg + j]);
    bf16* dst = Ctx + ((size_t)b*NQ + q0 + row)*DIM_ + h*DH + seg;
    *(uint4*)dst = pkv.u[0];
    *(uint4*)(dst+8) = pkv.u[1];
  }
}

// ------------------------------------------------------------------ launch
extern "C" void kernel_launch(void* const* d_in, const int* in_sizes, int n_in,
                              void* d_out, int out_size, void* d_ws, size_t ws_size,
                              hipStream_t stream)
{
  const float* query  = (const float*)d_in[0];
  const float* kv     = (const float*)d_in[1];
  const float* ln_q_g = (const float*)d_in[2];
  const float* ln_q_b = (const float*)d_in[3];
  const float* ln_kv_g= (const float*)d_in[4];
  const float* ln_kv_b= (const float*)d_in[5];
  const float* Wq = (const float*)d_in[6];
  const float* bq = (const float*)d_in[7];
  const float* Wk = (const float*)d_in[8];
  const float* bk = (const float*)d_in[9];
  const float* Wv = (const float*)d_in[10];
  const float* bv = (const float*)d_in[11];
  const float* Wo = (const float*)d_in[12];
  const float* bo = (const float*)d_in[13];
  float* out = (float*)d_out;

  char* ws = (char*)d_ws;
  size_t off = 0;
  auto take = [&](size_t bytes)->char* {
    char* p = ws + off; off += (bytes + 255) & ~(size_t)255; return p;
  };
  bf16* X    = (bf16*)take((size_t)B_*NT*DIM_*2);   // LN output (concat kv|q)
  bf16* Qhb  = (bf16*)take((size_t)B_*NQ*DIM_*2);   // head-major, pre-scaled
  bf16* Khb  = (bf16*)take((size_t)B_*NT*DIM_*2);   // head-major
  bf16* VTg  = (bf16*)take((size_t)DIM_*NSEQT*2);   // V^T [ch][b*NT+n]
  bf16* Ctx  = (bf16*)take((size_t)B_*NQ*DIM_*2);
  bf16* WtQ  = (bf16*)take((size_t)DIM_*DIM_*2);
  bf16* WtK  = (bf16*)take((size_t)DIM_*DIM_*2);
  bf16* WtV  = (bf16*)take((size_t)DIM_*DIM_*2);
  bf16* WtO  = (bf16*)take((size_t)DIM_*DIM_*2);

  prep2_kernel<<<3584, 256, 0, stream>>>(
      query, kv, ln_q_g, ln_q_b, ln_kv_g, ln_kv_b, X,
      Wq, Wk, Wv, Wo, WtQ, WtK, WtV, WtO);

  gemm_qkv5<<<1408, 256, 0, stream>>>(X, WtQ, WtK, WtV, bq, bk, bv,
                                      Qhb, Khb, VTg);

  attn6_kernel<<<512, 256, 0, stream>>>(Qhb, Khb, VTg, Ctx);

  gemm_o<<<128, 256, 0, stream>>>(Ctx, WtO, bo, query, out);
}

// Round 7
// 305.945 us; speedup vs baseline: 1.0042x; 1.0042x over previous
//
#include <hip/hip_runtime.h>
#include <hip/hip_bf16.h>

#define B_    4
#define NQ    512
#define NKV   2048
#define NT    2560     // NKV + NQ
#define DIM_  1024
#define HEADS 16
#define DH    64
#define NSEQT 10240    // B_*NT
// SCALE * log2(e): attention uses raw exp2
#define SCALE_Q_L2E 0.18033688011112042f

typedef short bf16x8 __attribute__((ext_vector_type(8)));
typedef float f32x4  __attribute__((ext_vector_type(4)));
typedef __hip_bfloat16 bf16;

// async global->LDS, 16B per lane. Global side may be a per-lane gather;
// LDS side is wave-uniform base + lane*16.
__device__ inline void gll16(const bf16* g, bf16* l) {
  __builtin_amdgcn_global_load_lds(
      (const __attribute__((address_space(1))) unsigned int*)g,
      (__attribute__((address_space(3))) unsigned int*)l, 16, 0, 0);
}

#define VMCNT(n) asm volatile("s_waitcnt vmcnt(" #n ")" ::: "memory")
#define BAR() __builtin_amdgcn_s_barrier()

// ---------------------------------------------- fused LayerNorm + weight^T
// blocks [0, 2560): LN, one WAVE per row (4 rows/block, no syncthreads).
// blocks [2560, 3584): 4x trw 64x64 weight transpose tiles.
__global__ __launch_bounds__(256) void prep2_kernel(
    const float* __restrict__ query, const float* __restrict__ kv,
    const float* __restrict__ lgq, const float* __restrict__ lbq,
    const float* __restrict__ lgkv, const float* __restrict__ lbkv,
    bf16* __restrict__ X,
    const float* __restrict__ W0, const float* __restrict__ W1,
    const float* __restrict__ W2, const float* __restrict__ W3,
    bf16* __restrict__ T0, bf16* __restrict__ T1,
    bf16* __restrict__ T2, bf16* __restrict__ T3)
{
  __shared__ __align__(16) char psm[9216];
  const int t = threadIdx.x;
  const int blkid = blockIdx.x;
  if (blkid < 2560) {
    const int w = t>>6, l = t&63;
    const int R = blkid*4 + w;                 // global row in X
    int b = R / NT, r = R % NT;
    const float *src, *gp, *bp;
    if (r < NKV) { src = kv    + ((size_t)b*NKV + r)*DIM_;      gp = lgkv; bp = lbkv; }
    else         { src = query + ((size_t)b*NQ + (r-NKV))*DIM_; gp = lgq;  bp = lbq;  }
    float4 v[4];
    #pragma unroll
    for (int j=0;j<4;++j) v[j] = ((const float4*)src)[j*64 + l];
    float s = 0.f, s2 = 0.f;
    #pragma unroll
    for (int j=0;j<4;++j){
      s  += v[j].x+v[j].y+v[j].z+v[j].w;
      s2 += v[j].x*v[j].x+v[j].y*v[j].y+v[j].z*v[j].z+v[j].w*v[j].w;
    }
    #pragma unroll
    for (int m=1;m<64;m<<=1){ s += __shfl_xor(s,m,64); s2 += __shfl_xor(s2,m,64); }
    float mu = s*(1.0f/DIM_);
    float rs = rsqrtf(s2*(1.0f/DIM_) - mu*mu + 1e-5f);
    uint2* drow = (uint2*)(X + (size_t)R*DIM_);
    #pragma unroll
    for (int j=0;j<4;++j){
      float4 gg = ((const float4*)gp)[j*64 + l];
      float4 b4 = ((const float4*)bp)[j*64 + l];
      union { unsigned int u[2]; bf16 h[4]; } pk;
      pk.h[0] = __float2bfloat16((v[j].x-mu)*rs*gg.x + b4.x);
      pk.h[1] = __float2bfloat16((v[j].y-mu)*rs*gg.y + b4.y);
      pk.h[2] = __float2bfloat16((v[j].z-mu)*rs*gg.z + b4.z);
      pk.h[3] = __float2bfloat16((v[j].w-mu)*rs*gg.w + b4.w);
      drow[j*64 + l] = make_uint2(pk.u[0], pk.u[1]);
    }
  } else {
    int l = blkid - 2560;
    const float* W; bf16* Wt;
    switch (l>>8) {
      case 0: W=W0; Wt=T0; break;
      case 1: W=W1; Wt=T1; break;
      case 2: W=W2; Wt=T2; break;
      default: W=W3; Wt=T3; break;
    }
    int rem = l & 255;
    int k0 = (rem&15)*64, n0 = (rem>>4)*64;
    bf16* Ws = (bf16*)psm;            // 64 x 72
    int kr = t>>2, nseg = (t&3)*16;
    const float4* s4 = (const float4*)(W + (size_t)(k0+kr)*DIM_ + n0 + nseg);
    union { uint4 u[2]; bf16 h[16]; } pk;
    #pragma unroll
    for (int j=0;j<4;j++){
      float4 v = s4[j];
      pk.h[j*4+0]=__float2bfloat16(v.x); pk.h[j*4+1]=__float2bfloat16(v.y);
      pk.h[j*4+2]=__float2bfloat16(v.z); pk.h[j*4+3]=__float2bfloat16(v.w);
    }
    *(uint4*)(Ws + kr*72 + nseg)     = pk.u[0];
    *(uint4*)(Ws + kr*72 + nseg + 8) = pk.u[1];
    __syncthreads();
    int n = t&63, kseg = t>>6;
    union { uint4 u[2]; bf16 h[16]; } o;
    #pragma unroll
    for (int k=0;k<16;k++) o.h[k] = Ws[(kseg*16+k)*72 + n];
    bf16* dst = Wt + (size_t)(n0+n)*DIM_ + k0 + kseg*16;
    *(uint4*)dst = o.u[0];
    *(uint4*)(dst+8) = o.u[1];
  }
}

// ------------------------------------------------------------- GEMM core v2
// (round-3 proven) 128x128 tile, BK=64, 4 waves (2x2), double-buffered 64 KiB
// LDS, granule-XOR swizzle (conflict-free ds_read_b128), one vmcnt(0)+barrier
// per K-tile, stages issued at tile top; 2 blocks/CU.
__device__ __forceinline__ void gemm_core2(
    const bf16* __restrict__ A, const bf16* __restrict__ Bmat,
    const float* __restrict__ bias, const float* __restrict__ residual,
    void* __restrict__ outv, int rows_per_batch, int row_offset,
    int a_batch_stride_rows, int n_seq, float scale,
    int emode, int m0, int n0, char* smem)
{
  char* const sA = smem;             // 2 x 16384
  char* const sB = smem + 32768;     // 2 x 16384
  float* Ts = (float*)smem;          // epilogue: 32 rows x stride 132

  const int t = threadIdx.x;
  const int srow = t >> 3;                 // 0..31: row within 32-row chunk
  const int gsw  = (t & 7) ^ (srow & 7);   // pre-swizzled source granule
  const bf16* pA[4]; const bf16* pB[4];
  #pragma unroll
  for (int c = 0; c < 4; ++c) {
    int gm = m0 + c*32 + srow;
    int bi = gm / rows_per_batch;
    pA[c] = A + ((size_t)bi*a_batch_stride_rows + row_offset
                 + (gm - bi*rows_per_batch))*(size_t)DIM_ + gsw*8;
    pB[c] = Bmat + (size_t)(n0 + c*32 + srow)*(size_t)DIM_ + gsw*8;
  }
  const int toff = t*16;

  const int wave = t>>6, lane = t&63, qq = lane>>4, mr = lane&15;
  const int wm = (wave>>1)*64, wn = (wave&1)*64;
  const int xq0 = (( qq    ) ^ (mr&7)) << 4;
  const int xq1 = ((4 + qq ) ^ (mr&7)) << 4;

  f32x4 acc[4][4] = {};

  // prologue: stage tile 0 -> buffer 0
  #pragma unroll
  for (int c=0;c<4;++c) gll16(pA[c], (bf16*)(sA + c*4096 + toff));
  #pragma unroll
  for (int c=0;c<4;++c) gll16(pB[c], (bf16*)(sB + c*4096 + toff));
  VMCNT(0);
  BAR();

  for (int kt = 0; kt < 16; ++kt) {
    const int cb = (kt&1) << 14;
    const int nb = ((kt+1)&1) << 14;
    if (kt < 15) {
      const int ko = (kt+1)*64;
      #pragma unroll
      for (int c=0;c<4;++c) gll16(pA[c] + ko, (bf16*)(sA + nb + c*4096 + toff));
      #pragma unroll
      for (int c=0;c<4;++c) gll16(pB[c] + ko, (bf16*)(sB + nb + c*4096 + toff));
    }
    #pragma unroll
    for (int kh = 0; kh < 2; ++kh) {
      const int xq = kh ? xq1 : xq0;
      bf16x8 af[4], bfr[4];
      #pragma unroll
      for (int ms=0; ms<4; ++ms)
        af[ms]  = *(const bf16x8*)(sA + cb + (wm + ms*16 + mr)*128 + xq);
      #pragma unroll
      for (int ns=0; ns<4; ++ns)
        bfr[ns] = *(const bf16x8*)(sB + cb + (wn + ns*16 + mr)*128 + xq);
      __builtin_amdgcn_s_setprio(1);
      #pragma unroll
      for (int ms=0; ms<4; ++ms)
        #pragma unroll
        for (int ns=0; ns<4; ++ns)
          acc[ms][ns] = __builtin_amdgcn_mfma_f32_16x16x32_bf16(
              af[ms], bfr[ns], acc[ms][ns], 0,0,0);
      __builtin_amdgcn_s_setprio(0);
    }
    VMCNT(0);   // own-wave next-tile stages landed; barrier joins all waves
    BAR();
  }
  __syncthreads();

  // epilogue: 4 rounds of 32 rows through LDS
  const int lr = t>>3, cs = (t&7)*16;
  for (int R=0; R<4; R++){
    if ((wave>>1) == (R>>1)) {
      #pragma unroll
      for (int ms2=0; ms2<2; ms2++){
        int ms = (R&1)*2 + ms2;
        #pragma unroll
        for (int ns=0; ns<4; ns++){
          int col = wn + ns*16 + mr;
          #pragma unroll
          for (int r=0;r<4;r++)
            Ts[(ms2*16 + qq*4 + r)*132 + col] = acc[ms][ns][r];
        }
      }
    }
    __syncthreads();
    float v[16];
    #pragma unroll
    for (int j=0;j<4;j++){
      float4 f = *(const float4*)(Ts + lr*132 + cs + j*4);
      v[j*4+0]=f.x; v[j*4+1]=f.y; v[j*4+2]=f.z; v[j*4+3]=f.w;
    }
    int gr = m0 + R*32 + lr;
    int gc = n0 + cs;
    if (emode == 0) {
      float* out = (float*)outv;
      size_t base = (size_t)gr*DIM_ + gc;
      #pragma unroll
      for (int j=0;j<4;j++){
        float4 bv = *(const float4*)(bias + gc + j*4);
        float4 rv = *(const float4*)(residual + base + j*4);
        float4 o4;
        o4.x = v[j*4+0] + bv.x + rv.x;
        o4.y = v[j*4+1] + bv.y + rv.y;
        o4.z = v[j*4+2] + bv.z + rv.z;
        o4.w = v[j*4+3] + bv.w + rv.w;
        *(float4*)(out + base + j*4) = o4;
      }
    } else if (emode == 1) {
      int bb = gr / rows_per_batch;
      int n  = gr - bb*rows_per_batch;
      int hh = gc>>6, dh = gc&63;
      bf16* out = (bf16*)outv + ((size_t)(bb*HEADS + hh)*n_seq + n)*DH + dh;
      union { uint4 u[2]; bf16 h[16]; } pk;
      #pragma unroll
      for (int j=0;j<16;j++) pk.h[j] = __float2bfloat16((v[j] + bias[gc+j])*scale);
      *(uint4*)out     = pk.u[0];
      *(uint4*)(out+8) = pk.u[1];
    } else {
      float bc = bias[gr];
      bf16* out = (bf16*)outv + (size_t)gr*NSEQT + gc;
      union { uint4 u[2]; bf16 h[16]; } pk;
      #pragma unroll
      for (int j=0;j<16;j++) pk.h[j] = __float2bfloat16(v[j] + bc);
      *(uint4*)out     = pk.u[0];
      *(uint4*)(out+8) = pk.u[1];
    }
    __syncthreads();
  }
}

// -------------------------------------------- fused Q/K/V projection GEMMs
__global__ __launch_bounds__(256) void gemm_qkv3(
    const bf16* __restrict__ X,
    const bf16* __restrict__ WtQ, const bf16* __restrict__ WtK,
    const bf16* __restrict__ WtV,
    const float* __restrict__ bq, const float* __restrict__ bk,
    const float* __restrict__ bv,
    bf16* __restrict__ Qhb, bf16* __restrict__ Khb, bf16* __restrict__ VTg)
{
  __shared__ __align__(16) char smem[65536];
  const int blk = blockIdx.x;
  if (blk < 128) {
    gemm_core2(X, WtQ, bq, nullptr, Qhb, NQ, NKV, NT, NQ, SCALE_Q_L2E, 1,
               (blk&15)*128, (blk>>4)*128, smem);
  } else if (blk < 768) {
    int l = blk - 128;
    gemm_core2(X, WtK, bk, nullptr, Khb, NT, 0, NT, NT, 1.0f, 1,
               (l%80)*128, (l/80)*128, smem);
  } else {
    int l = blk - 768;
    gemm_core2(WtV, X, bv, nullptr, VTg, DIM_, 0, DIM_, NSEQT, 1.0f, 2,
               (l/80)*128, (l%80)*128, smem);
  }
}

// ------------------------------------------------ output projection GEMM
__global__ __launch_bounds__(256) void gemm_o(
    const bf16* __restrict__ Ctx, const bf16* __restrict__ WtO,
    const float* __restrict__ bo, const float* __restrict__ residual,
    float* __restrict__ out)
{
  __shared__ __align__(16) char smem[65536];
  const int blk = blockIdx.x;
  gemm_core2(Ctx, WtO, bo, residual, out, B_*NQ, 0, B_*NQ, NQ, 1.0f, 0,
             (blk&15)*128, (blk>>4)*128, smem);
}

// --------------------------------------------------------------- Attention
// attn8 = attn6 + PADDED K/V LDS rows (72B stride) to kill the 8-way bank
// conflict on kf/vf ds_read_b128 (64B rows alias banks every 2 rows).
// gll16 can't target padded rows, so staging is register-staged (T14 split):
// global uint4 loads for tile it+1 issue at iteration top, ds_write_b128 to
// the padded buffer at iteration end (before the barrier). Same logical
// layout as attn6 (skey interleave, packed-pair P, cross-pair merge).
// LDS: 2 bufs x 4 chunks x 64 rows x 72B = 36864B + Ps 10240B.
__global__ __launch_bounds__(256) void attn8_kernel(
    const bf16* __restrict__ Qh, const bf16* __restrict__ Kh,
    const bf16* __restrict__ VTg, bf16* __restrict__ Ctx)
{
  __shared__ __align__(16) char KVp[2][18432];        // padded K/V buffers
  __shared__ __align__(16) unsigned int Ps[4][640];   // per-wave P: 32 rows x 20 words

  const int t = threadIdx.x, wave = t>>6, lane = t&63;
  const int qq = lane>>4, mr = lane&15;
  const int blk = blockIdx.x;
  const int bh = (blk&7)*8 + (blk>>6);      // same bh -> same blk%8 slot (XCD)
  const int q0 = ((blk>>3)&7)*64;
  const int b = bh>>4, h = bh&15;
  const int pair = wave>>1, kh = wave&1;
  const int qb = pair*32;

  const int sl = t>>2, sc = t&3;
  const int skey = 32*(sl>>5) + 2*(sl&15) + ((sl>>4)&1);
  const bf16* Kb  = Kh + (size_t)bh*NT*DH + (size_t)skey*DH + sc*8;
  const bf16* VbT = VTg + ((size_t)(h*DH) + sl)*NSEQT + (size_t)b*NT + sc*8;
  const int wb = sl*72 + sc*16;             // padded write offset (bytes)

  // Q fragments for this wave's 32 q-rows (two 16-row subtiles)
  bf16x8 qf[2][2];
  #pragma unroll
  for (int mt=0; mt<2; mt++){
    const bf16* Qb = Qh + ((size_t)bh*NQ + q0 + qb + mt*16 + mr)*DH;
    qf[mt][0] = *(const bf16x8*)(Qb + qq*8);
    qf[mt][1] = *(const bf16x8*)(Qb + 32 + qq*8);
  }

  f32x4 o[2][4] = {};
  float l[2][4] = {};
  unsigned int* Pw = &Ps[wave][0];
  const int NIT = NT/64;   // 40

  // prologue: load tile 0 -> regs -> padded buf 0
  {
    uint4 r0 = *(const uint4*)(Kb);
    uint4 r1 = *(const uint4*)(Kb + 32);
    uint4 r2 = *(const uint4*)(VbT);
    uint4 r3 = *(const uint4*)(VbT + 32);
    char* bp = &KVp[0][0];
    *(uint4*)(bp + wb)         = r0;
    *(uint4*)(bp + 4608 + wb)  = r1;
    *(uint4*)(bp + 9216 + wb)  = r2;
    *(uint4*)(bp + 13824 + wb) = r3;
  }

  for (int it = 0; it < NIT; it++) {
    __syncthreads();
    // issue loads for tile it+1 (clamped redundant load on last iter)
    const int nt2 = ((it+1 < NIT) ? it+1 : NIT-1)*64;
    uint4 r0 = *(const uint4*)(Kb + (size_t)nt2*DH);
    uint4 r1 = *(const uint4*)(Kb + (size_t)nt2*DH + 32);
    uint4 r2 = *(const uint4*)(VbT + nt2);
    uint4 r3 = *(const uint4*)(VbT + nt2 + 32);

    const char* cb = &KVp[it&1][0];

    // K fragments: this wave's key half, 2 subtiles of 16 keys
    bf16x8 kf[2][2];
    #pragma unroll
    for (int g=0; g<2; g++){
      kf[g][0] = *(const bf16x8*)(cb + (32*kh + 16*g + mr)*72 + qq*16);
      kf[g][1] = *(const bf16x8*)(cb + 4608 + (32*kh + 16*g + mr)*72 + qq*16);
    }
    f32x4 s[2][2];
    __builtin_amdgcn_s_setprio(1);
    #pragma unroll
    for (int mt=0; mt<2; mt++)
      #pragma unroll
      for (int g=0; g<2; g++){
        f32x4 z = {};
        z = __builtin_amdgcn_mfma_f32_16x16x32_bf16(qf[mt][0], kf[g][0], z, 0,0,0);
        z = __builtin_amdgcn_mfma_f32_16x16x32_bf16(qf[mt][1], kf[g][1], z, 0,0,0);
        s[mt][g] = z;
      }
    __builtin_amdgcn_s_setprio(0);
    // V fragments: this wave's key-half panel (channels n2*16+mr)
    bf16x8 vf[4];
    #pragma unroll
    for (int n2=0; n2<4; n2++)
      vf[n2] = *(const bf16x8*)(cb + 9216 + kh*4608 + (n2*16+mr)*72 + qq*16);

    // exp2 + pack pair (keys 2mr, 2mr+1 of the half) -> one word per q-row
    #pragma unroll
    for (int mt=0; mt<2; mt++)
      #pragma unroll
      for (int r=0; r<4; r++){
        float e0 = __builtin_amdgcn_exp2f(s[mt][0][r]);
        float e1 = __builtin_amdgcn_exp2f(s[mt][1][r]);
        l[mt][r] += e0 + e1;
        unsigned a0 = __float_as_uint(e0) + 0x8000u;
        unsigned a1 = __float_as_uint(e1) + 0x8000u;
        Pw[(mt*16 + qq*4 + r)*20 + mr] = __builtin_amdgcn_perm(a1, a0, 0x07060302u);
      }
    asm volatile("s_waitcnt lgkmcnt(0)" ::: "memory");
    bf16x8 pa[2];
    #pragma unroll
    for (int mt=0; mt<2; mt++)
      pa[mt] = *(const bf16x8*)(Pw + (mt*16+mr)*20 + qq*4);
    __builtin_amdgcn_s_setprio(1);
    #pragma unroll
    for (int mt=0; mt<2; mt++)
      #pragma unroll
      for (int n2=0; n2<4; n2++)
        o[mt][n2] = __builtin_amdgcn_mfma_f32_16x16x32_bf16(pa[mt], vf[n2], o[mt][n2], 0,0,0);
    __builtin_amdgcn_s_setprio(0);

    // write tile it+1 into the other buffer (its readers finished before
    // this iteration's top barrier; lgkm drained by next syncthreads)
    {
      char* np = &KVp[(it+1)&1][0];
      *(uint4*)(np + wb)         = r0;
      *(uint4*)(np + 4608 + wb)  = r1;
      *(uint4*)(np + 9216 + wb)  = r2;
      *(uint4*)(np + 13824 + wb) = r3;
    }
  }

  // partial row sums over this wave's key half
  float lsum[2][4];
  #pragma unroll
  for (int mt=0; mt<2; mt++)
    #pragma unroll
    for (int r=0; r<4; r++){
      float v = l[mt][r];
      #pragma unroll
      for (int m=1;m<16;m<<=1) v += __shfl_xor(v, m, 16);
      lsum[mt][r] = v;
    }

  // cross-pair merge via LDS (waves kh=1 publish, kh=0 merge+normalize)
  __syncthreads();
  float* Of  = (float*)&KVp[0][0];  // 64 rows x stride 68 f32 (17408 B)
  float* lsh = (float*)&Ps[0][0];   // 64 f32
  if (kh == 1) {
    #pragma unroll
    for (int mt=0; mt<2; mt++){
      #pragma unroll
      for (int n2=0; n2<4; n2++)
        #pragma unroll
        for (int r=0; r<4; r++)
          Of[(qb + mt*16 + qq*4 + r)*68 + n2*16 + mr] = o[mt][n2][r];
      if (mr == 0)
        #pragma unroll
        for (int r=0; r<4; r++)
          lsh[qb + mt*16 + qq*4 + r] = lsum[mt][r];
    }
  }
  __syncthreads();
  if (kh == 0) {
    #pragma unroll
    for (int mt=0; mt<2; mt++)
      #pragma unroll
      for (int r=0; r<4; r++){
        int row = qb + mt*16 + qq*4 + r;
        float rl = 1.0f / (lsum[mt][r] + lsh[row]);
        #pragma unroll
        for (int n2=0; n2<4; n2++){
          int idx = row*68 + n2*16 + mr;
          Of[idx] = (o[mt][n2][r] + Of[idx]) * rl;
        }
      }
  }
  __syncthreads();
  // vectorized store: each thread writes 16 bf16 of one row
  {
    int row = t>>2, seg = (t&3)*16;
    union { uint4 u[2]; bf16 hh[16]; } pkv;
    #pragma unroll
    for (int j=0;j<16;j++) pkv.hh[j] = __float2bfloat16(Of[row*68 + seg + j]);
    bf16* dst = Ctx + ((size_t)b*NQ + q0 + row)*DIM_ + h*DH + seg;
    *(uint4*)dst = pkv.u[0];
    *(uint4*)(dst+8) = pkv.u[1];
  }
}

// ------------------------------------------------------------------ launch
extern "C" void kernel_launch(void* const* d_in, const int* in_sizes, int n_in,
                              void* d_out, int out_size, void* d_ws, size_t ws_size,
                              hipStream_t stream)
{
  const float* query  = (const float*)d_in[0];
  const float* kv     = (const float*)d_in[1];
  const float* ln_q_g = (const float*)d_in[2];
  const float* ln_q_b = (const float*)d_in[3];
  const float* ln_kv_g= (const float*)d_in[4];
  const float* ln_kv_b= (const float*)d_in[5];
  const float* Wq = (const float*)d_in[6];
  const float* bq = (const float*)d_in[7];
  const float* Wk = (const float*)d_in[8];
  const float* bk = (const float*)d_in[9];
  const float* Wv = (const float*)d_in[10];
  const float* bv = (const float*)d_in[11];
  const float* Wo = (const float*)d_in[12];
  const float* bo = (const float*)d_in[13];
  float* out = (float*)d_out;

  char* ws = (char*)d_ws;
  size_t off = 0;
  auto take = [&](size_t bytes)->char* {
    char* p = ws + off; off += (bytes + 255) & ~(size_t)255; return p;
  };
  bf16* X    = (bf16*)take((size_t)B_*NT*DIM_*2);   // LN output (concat kv|q)
  bf16* Qhb  = (bf16*)take((size_t)B_*NQ*DIM_*2);   // head-major, pre-scaled
  bf16* Khb  = (bf16*)take((size_t)B_*NT*DIM_*2);   // head-major
  bf16* VTg  = (bf16*)take((size_t)DIM_*NSEQT*2);   // V^T [ch][b*NT+n]
  bf16* Ctx  = (bf16*)take((size_t)B_*NQ*DIM_*2);
  bf16* WtQ  = (bf16*)take((size_t)DIM_*DIM_*2);
  bf16* WtK  = (bf16*)take((size_t)DIM_*DIM_*2);
  bf16* WtV  = (bf16*)take((size_t)DIM_*DIM_*2);
  bf16* WtO  = (bf16*)take((size_t)DIM_*DIM_*2);

  prep2_kernel<<<3584, 256, 0, stream>>>(
      query, kv, ln_q_g, ln_q_b, ln_kv_g, ln_kv_b, X,
      Wq, Wk, Wv, Wo, WtQ, WtK, WtV, WtO);

  gemm_qkv3<<<1408, 256, 0, stream>>>(X, WtQ, WtK, WtV, bq, bk, bv,
                                      Qhb, Khb, VTg);

  attn8_kernel<<<512, 256, 0, stream>>>(Qhb, Khb, VTg, Ctx);

  gemm_o<<<128, 256, 0, stream>>>(Ctx, WtO, bo, query, out);
}

// Round 8
// 239.013 us; speedup vs baseline: 1.2854x; 1.2800x over previous
//
#include <hip/hip_runtime.h>
#include <hip/hip_bf16.h>

#define B_    4
#define NQ    512
#define NKV   2048
#define NT    2560     // NKV + NQ
#define DIM_  1024
#define HEADS 16
#define DH    64
#define NSEQT 10240    // B_*NT
// SCALE * log2(e): attention uses raw exp2
#define SCALE_Q_L2E 0.18033688011112042f

typedef short bf16x8 __attribute__((ext_vector_type(8)));
typedef float f32x4  __attribute__((ext_vector_type(4)));
typedef __hip_bfloat16 bf16;

// async global->LDS, 16B per lane. Global side may be a per-lane gather;
// LDS side is wave-uniform base + lane*16.
__device__ inline void gll16(const bf16* g, bf16* l) {
  __builtin_amdgcn_global_load_lds(
      (const __attribute__((address_space(1))) unsigned int*)g,
      (__attribute__((address_space(3))) unsigned int*)l, 16, 0, 0);
}

#define VMCNT(n) asm volatile("s_waitcnt vmcnt(" #n ")" ::: "memory")
#define BAR() __builtin_amdgcn_s_barrier()

// ---------------------------------------------- fused LayerNorm + weight^T
// blocks [0, 2560): LN, one WAVE per row (4 rows/block, no syncthreads).
// blocks [2560, 3584): 4x trw 64x64 weight transpose tiles.
__global__ __launch_bounds__(256) void prep2_kernel(
    const float* __restrict__ query, const float* __restrict__ kv,
    const float* __restrict__ lgq, const float* __restrict__ lbq,
    const float* __restrict__ lgkv, const float* __restrict__ lbkv,
    bf16* __restrict__ X,
    const float* __restrict__ W0, const float* __restrict__ W1,
    const float* __restrict__ W2, const float* __restrict__ W3,
    bf16* __restrict__ T0, bf16* __restrict__ T1,
    bf16* __restrict__ T2, bf16* __restrict__ T3)
{
  __shared__ __align__(16) char psm[9216];
  const int t = threadIdx.x;
  const int blkid = blockIdx.x;
  if (blkid < 2560) {
    const int w = t>>6, l = t&63;
    const int R = blkid*4 + w;                 // global row in X
    int b = R / NT, r = R % NT;
    const float *src, *gp, *bp;
    if (r < NKV) { src = kv    + ((size_t)b*NKV + r)*DIM_;      gp = lgkv; bp = lbkv; }
    else         { src = query + ((size_t)b*NQ + (r-NKV))*DIM_; gp = lgq;  bp = lbq;  }
    float4 v[4];
    #pragma unroll
    for (int j=0;j<4;++j) v[j] = ((const float4*)src)[j*64 + l];
    float s = 0.f, s2 = 0.f;
    #pragma unroll
    for (int j=0;j<4;++j){
      s  += v[j].x+v[j].y+v[j].z+v[j].w;
      s2 += v[j].x*v[j].x+v[j].y*v[j].y+v[j].z*v[j].z+v[j].w*v[j].w;
    }
    #pragma unroll
    for (int m=1;m<64;m<<=1){ s += __shfl_xor(s,m,64); s2 += __shfl_xor(s2,m,64); }
    float mu = s*(1.0f/DIM_);
    float rs = rsqrtf(s2*(1.0f/DIM_) - mu*mu + 1e-5f);
    uint2* drow = (uint2*)(X + (size_t)R*DIM_);
    #pragma unroll
    for (int j=0;j<4;++j){
      float4 gg = ((const float4*)gp)[j*64 + l];
      float4 b4 = ((const float4*)bp)[j*64 + l];
      union { unsigned int u[2]; bf16 h[4]; } pk;
      pk.h[0] = __float2bfloat16((v[j].x-mu)*rs*gg.x + b4.x);
      pk.h[1] = __float2bfloat16((v[j].y-mu)*rs*gg.y + b4.y);
      pk.h[2] = __float2bfloat16((v[j].z-mu)*rs*gg.z + b4.z);
      pk.h[3] = __float2bfloat16((v[j].w-mu)*rs*gg.w + b4.w);
      drow[j*64 + l] = make_uint2(pk.u[0], pk.u[1]);
    }
  } else {
    int l = blkid - 2560;
    const float* W; bf16* Wt;
    switch (l>>8) {
      case 0: W=W0; Wt=T0; break;
      case 1: W=W1; Wt=T1; break;
      case 2: W=W2; Wt=T2; break;
      default: W=W3; Wt=T3; break;
    }
    int rem = l & 255;
    int k0 = (rem&15)*64, n0 = (rem>>4)*64;
    bf16* Ws = (bf16*)psm;            // 64 x 72
    int kr = t>>2, nseg = (t&3)*16;
    const float4* s4 = (const float4*)(W + (size_t)(k0+kr)*DIM_ + n0 + nseg);
    union { uint4 u[2]; bf16 h[16]; } pk;
    #pragma unroll
    for (int j=0;j<4;j++){
      float4 v = s4[j];
      pk.h[j*4+0]=__float2bfloat16(v.x); pk.h[j*4+1]=__float2bfloat16(v.y);
      pk.h[j*4+2]=__float2bfloat16(v.z); pk.h[j*4+3]=__float2bfloat16(v.w);
    }
    *(uint4*)(Ws + kr*72 + nseg)     = pk.u[0];
    *(uint4*)(Ws + kr*72 + nseg + 8) = pk.u[1];
    __syncthreads();
    int n = t&63, kseg = t>>6;
    union { uint4 u[2]; bf16 h[16]; } o;
    #pragma unroll
    for (int k=0;k<16;k++) o.h[k] = Ws[(kseg*16+k)*72 + n];
    bf16* dst = Wt + (size_t)(n0+n)*DIM_ + k0 + kseg*16;
    *(uint4*)dst = o.u[0];
    *(uint4*)(dst+8) = o.u[1];
  }
}

// ------------------------------------------------------------- GEMM core v2
// (round-3 proven) 128x128 tile, BK=64, 4 waves (2x2), double-buffered 64 KiB
// LDS, granule-XOR swizzle (conflict-free ds_read_b128), one vmcnt(0)+barrier
// per K-tile, stages issued at tile top; 2 blocks/CU.
__device__ __forceinline__ void gemm_core2(
    const bf16* __restrict__ A, const bf16* __restrict__ Bmat,
    const float* __restrict__ bias, const float* __restrict__ residual,
    void* __restrict__ outv, int rows_per_batch, int row_offset,
    int a_batch_stride_rows, int n_seq, float scale,
    int emode, int m0, int n0, char* smem)
{
  char* const sA = smem;             // 2 x 16384
  char* const sB = smem + 32768;     // 2 x 16384
  float* Ts = (float*)smem;          // epilogue: 32 rows x stride 132

  const int t = threadIdx.x;
  const int srow = t >> 3;                 // 0..31: row within 32-row chunk
  const int gsw  = (t & 7) ^ (srow & 7);   // pre-swizzled source granule
  const bf16* pA[4]; const bf16* pB[4];
  #pragma unroll
  for (int c = 0; c < 4; ++c) {
    int gm = m0 + c*32 + srow;
    int bi = gm / rows_per_batch;
    pA[c] = A + ((size_t)bi*a_batch_stride_rows + row_offset
                 + (gm - bi*rows_per_batch))*(size_t)DIM_ + gsw*8;
    pB[c] = Bmat + (size_t)(n0 + c*32 + srow)*(size_t)DIM_ + gsw*8;
  }
  const int toff = t*16;

  const int wave = t>>6, lane = t&63, qq = lane>>4, mr = lane&15;
  const int wm = (wave>>1)*64, wn = (wave&1)*64;
  const int xq0 = (( qq    ) ^ (mr&7)) << 4;
  const int xq1 = ((4 + qq ) ^ (mr&7)) << 4;

  f32x4 acc[4][4] = {};

  // prologue: stage tile 0 -> buffer 0
  #pragma unroll
  for (int c=0;c<4;++c) gll16(pA[c], (bf16*)(sA + c*4096 + toff));
  #pragma unroll
  for (int c=0;c<4;++c) gll16(pB[c], (bf16*)(sB + c*4096 + toff));
  VMCNT(0);
  BAR();

  for (int kt = 0; kt < 16; ++kt) {
    const int cb = (kt&1) << 14;
    const int nb = ((kt+1)&1) << 14;
    if (kt < 15) {
      const int ko = (kt+1)*64;
      #pragma unroll
      for (int c=0;c<4;++c) gll16(pA[c] + ko, (bf16*)(sA + nb + c*4096 + toff));
      #pragma unroll
      for (int c=0;c<4;++c) gll16(pB[c] + ko, (bf16*)(sB + nb + c*4096 + toff));
    }
    #pragma unroll
    for (int kh = 0; kh < 2; ++kh) {
      const int xq = kh ? xq1 : xq0;
      bf16x8 af[4], bfr[4];
      #pragma unroll
      for (int ms=0; ms<4; ++ms)
        af[ms]  = *(const bf16x8*)(sA + cb + (wm + ms*16 + mr)*128 + xq);
      #pragma unroll
      for (int ns=0; ns<4; ++ns)
        bfr[ns] = *(const bf16x8*)(sB + cb + (wn + ns*16 + mr)*128 + xq);
      __builtin_amdgcn_s_setprio(1);
      #pragma unroll
      for (int ms=0; ms<4; ++ms)
        #pragma unroll
        for (int ns=0; ns<4; ++ns)
          acc[ms][ns] = __builtin_amdgcn_mfma_f32_16x16x32_bf16(
              af[ms], bfr[ns], acc[ms][ns], 0,0,0);
      __builtin_amdgcn_s_setprio(0);
    }
    VMCNT(0);   // own-wave next-tile stages landed; barrier joins all waves
    BAR();
  }
  __syncthreads();

  // epilogue: 4 rounds of 32 rows through LDS
  const int lr = t>>3, cs = (t&7)*16;
  for (int R=0; R<4; R++){
    if ((wave>>1) == (R>>1)) {
      #pragma unroll
      for (int ms2=0; ms2<2; ms2++){
        int ms = (R&1)*2 + ms2;
        #pragma unroll
        for (int ns=0; ns<4; ns++){
          int col = wn + ns*16 + mr;
          #pragma unroll
          for (int r=0;r<4;r++)
            Ts[(ms2*16 + qq*4 + r)*132 + col] = acc[ms][ns][r];
        }
      }
    }
    __syncthreads();
    float v[16];
    #pragma unroll
    for (int j=0;j<4;j++){
      float4 f = *(const float4*)(Ts + lr*132 + cs + j*4);
      v[j*4+0]=f.x; v[j*4+1]=f.y; v[j*4+2]=f.z; v[j*4+3]=f.w;
    }
    int gr = m0 + R*32 + lr;
    int gc = n0 + cs;
    if (emode == 0) {
      float* out = (float*)outv;
      size_t base = (size_t)gr*DIM_ + gc;
      #pragma unroll
      for (int j=0;j<4;j++){
        float4 bv = *(const float4*)(bias + gc + j*4);
        float4 rv = *(const float4*)(residual + base + j*4);
        float4 o4;
        o4.x = v[j*4+0] + bv.x + rv.x;
        o4.y = v[j*4+1] + bv.y + rv.y;
        o4.z = v[j*4+2] + bv.z + rv.z;
        o4.w = v[j*4+3] + bv.w + rv.w;
        *(float4*)(out + base + j*4) = o4;
      }
    } else if (emode == 1) {
      int bb = gr / rows_per_batch;
      int n  = gr - bb*rows_per_batch;
      int hh = gc>>6, dh = gc&63;
      bf16* out = (bf16*)outv + ((size_t)(bb*HEADS + hh)*n_seq + n)*DH + dh;
      union { uint4 u[2]; bf16 h[16]; } pk;
      #pragma unroll
      for (int j=0;j<16;j++) pk.h[j] = __float2bfloat16((v[j] + bias[gc+j])*scale);
      *(uint4*)out     = pk.u[0];
      *(uint4*)(out+8) = pk.u[1];
    } else {
      float bc = bias[gr];
      bf16* out = (bf16*)outv + (size_t)gr*NSEQT + gc;
      union { uint4 u[2]; bf16 h[16]; } pk;
      #pragma unroll
      for (int j=0;j<16;j++) pk.h[j] = __float2bfloat16(v[j] + bc);
      *(uint4*)out     = pk.u[0];
      *(uint4*)(out+8) = pk.u[1];
    }
    __syncthreads();
  }
}

// -------------------------------------------- fused Q/K/V projection GEMMs
__global__ __launch_bounds__(256) void gemm_qkv3(
    const bf16* __restrict__ X,
    const bf16* __restrict__ WtQ, const bf16* __restrict__ WtK,
    const bf16* __restrict__ WtV,
    const float* __restrict__ bq, const float* __restrict__ bk,
    const float* __restrict__ bv,
    bf16* __restrict__ Qhb, bf16* __restrict__ Khb, bf16* __restrict__ VTg)
{
  __shared__ __align__(16) char smem[65536];
  const int blk = blockIdx.x;
  if (blk < 128) {
    gemm_core2(X, WtQ, bq, nullptr, Qhb, NQ, NKV, NT, NQ, SCALE_Q_L2E, 1,
               (blk&15)*128, (blk>>4)*128, smem);
  } else if (blk < 768) {
    int l = blk - 128;
    gemm_core2(X, WtK, bk, nullptr, Khb, NT, 0, NT, NT, 1.0f, 1,
               (l%80)*128, (l/80)*128, smem);
  } else {
    int l = blk - 768;
    gemm_core2(WtV, X, bv, nullptr, VTg, DIM_, 0, DIM_, NSEQT, 1.0f, 2,
               (l/80)*128, (l%80)*128, smem);
  }
}

// ------------------------------------------------------- GEMM core v2h
// 64x128 tile variant of core2 (halved M): 4 waves 2x2, per-wave 32 rows
// (acc[2][4]), A = 2 chunks (16 KiB dbuf), B unchanged (32 KiB dbuf).
// Used by gemm_o to fill all 256 CUs (256 blocks instead of 128).
__device__ __forceinline__ void gemm_core2h(
    const bf16* __restrict__ A, const bf16* __restrict__ Bmat,
    const float* __restrict__ bias, const float* __restrict__ residual,
    float* __restrict__ out, int m0, int n0, char* smem)
{
  char* const sA = smem;             // 2 x 8192
  char* const sB = smem + 16384;     // 2 x 16384
  float* Ts = (float*)smem;          // epilogue: 32 rows x stride 132

  const int t = threadIdx.x;
  const int srow = t >> 3;
  const int gsw  = (t & 7) ^ (srow & 7);
  const bf16* pA[2]; const bf16* pB[4];
  #pragma unroll
  for (int c = 0; c < 2; ++c)
    pA[c] = A + (size_t)(m0 + c*32 + srow)*(size_t)DIM_ + gsw*8;
  #pragma unroll
  for (int c = 0; c < 4; ++c)
    pB[c] = Bmat + (size_t)(n0 + c*32 + srow)*(size_t)DIM_ + gsw*8;
  const int toff = t*16;

  const int wave = t>>6, lane = t&63, qq = lane>>4, mr = lane&15;
  const int wm = (wave>>1)*32, wn = (wave&1)*64;
  const int xq0 = (( qq    ) ^ (mr&7)) << 4;
  const int xq1 = ((4 + qq ) ^ (mr&7)) << 4;

  f32x4 acc[2][4] = {};

  #pragma unroll
  for (int c=0;c<2;++c) gll16(pA[c], (bf16*)(sA + c*4096 + toff));
  #pragma unroll
  for (int c=0;c<4;++c) gll16(pB[c], (bf16*)(sB + c*4096 + toff));
  VMCNT(0);
  BAR();

  for (int kt = 0; kt < 16; ++kt) {
    const int cba = (kt&1) << 13, cbb = (kt&1) << 14;
    const int nba = ((kt+1)&1) << 13, nbb = ((kt+1)&1) << 14;
    if (kt < 15) {
      const int ko = (kt+1)*64;
      #pragma unroll
      for (int c=0;c<2;++c) gll16(pA[c] + ko, (bf16*)(sA + nba + c*4096 + toff));
      #pragma unroll
      for (int c=0;c<4;++c) gll16(pB[c] + ko, (bf16*)(sB + nbb + c*4096 + toff));
    }
    #pragma unroll
    for (int kh = 0; kh < 2; ++kh) {
      const int xq = kh ? xq1 : xq0;
      bf16x8 af[2], bfr[4];
      #pragma unroll
      for (int ms=0; ms<2; ++ms)
        af[ms]  = *(const bf16x8*)(sA + cba + (wm + ms*16 + mr)*128 + xq);
      #pragma unroll
      for (int ns=0; ns<4; ++ns)
        bfr[ns] = *(const bf16x8*)(sB + cbb + (wn + ns*16 + mr)*128 + xq);
      __builtin_amdgcn_s_setprio(1);
      #pragma unroll
      for (int ms=0; ms<2; ++ms)
        #pragma unroll
        for (int ns=0; ns<4; ++ns)
          acc[ms][ns] = __builtin_amdgcn_mfma_f32_16x16x32_bf16(
              af[ms], bfr[ns], acc[ms][ns], 0,0,0);
      __builtin_amdgcn_s_setprio(0);
    }
    VMCNT(0);
    BAR();
  }
  __syncthreads();

  // epilogue: 2 rounds of 32 rows through LDS
  const int lr = t>>3, cs = (t&7)*16;
  for (int R=0; R<2; R++){
    if ((wave>>1) == R) {
      #pragma unroll
      for (int ms=0; ms<2; ms++){
        #pragma unroll
        for (int ns=0; ns<4; ns++){
          int col = wn + ns*16 + mr;
          #pragma unroll
          for (int r=0;r<4;r++)
            Ts[(ms*16 + qq*4 + r)*132 + col] = acc[ms][ns][r];
        }
      }
    }
    __syncthreads();
    float v[16];
    #pragma unroll
    for (int j=0;j<4;j++){
      float4 f = *(const float4*)(Ts + lr*132 + cs + j*4);
      v[j*4+0]=f.x; v[j*4+1]=f.y; v[j*4+2]=f.z; v[j*4+3]=f.w;
    }
    int gr = m0 + R*32 + lr;
    int gc = n0 + cs;
    size_t base = (size_t)gr*DIM_ + gc;
    #pragma unroll
    for (int j=0;j<4;j++){
      float4 bv = *(const float4*)(bias + gc + j*4);
      float4 rv = *(const float4*)(residual + base + j*4);
      float4 o4;
      o4.x = v[j*4+0] + bv.x + rv.x;
      o4.y = v[j*4+1] + bv.y + rv.y;
      o4.z = v[j*4+2] + bv.z + rv.z;
      o4.w = v[j*4+3] + bv.w + rv.w;
      *(float4*)(out + base + j*4) = o4;
    }
    __syncthreads();
  }
}

// ------------------------------------------------ output projection GEMM
// 256 blocks of 64x128 tiles: every CU gets one block (was 128 blocks ->
// half the GPU idle).
__global__ __launch_bounds__(256) void gemm_o2(
    const bf16* __restrict__ Ctx, const bf16* __restrict__ WtO,
    const float* __restrict__ bo, const float* __restrict__ residual,
    float* __restrict__ out)
{
  __shared__ __align__(16) char smem[49152];
  const int blk = blockIdx.x;
  gemm_core2h(Ctx, WtO, bo, residual, out,
              (blk&31)*64, (blk>>5)*128, smem);
}

// --------------------------------------------------------------- Attention
// attn6 (round-3 proven): block = 64 q-rows of one (b,h). Wave w: q-rows
// (w>>1)*32..+31, key half (w&1)*32 of each 64-key tile. K staged
// key-interleaved; packed-pair P words; cross-pair O/l merge via LDS.
__global__ __launch_bounds__(256) void attn6_kernel(
    const bf16* __restrict__ Qh, const bf16* __restrict__ Kh,
    const bf16* __restrict__ VTg, bf16* __restrict__ Ctx)
{
  __shared__ __align__(16) bf16 KV[2][8192];          // 32 KB (2 buffers)
  __shared__ __align__(16) unsigned int Ps[4][640];   // per-wave P: 32 rows x 20 words

  const int t = threadIdx.x, wave = t>>6, lane = t&63;
  const int qq = lane>>4, mr = lane&15;
  const int blk = blockIdx.x;
  const int bh = (blk&7)*8 + (blk>>6);      // same bh -> same blk%8 slot (XCD)
  const int q0 = ((blk>>3)&7)*64;
  const int b = bh>>4, h = bh&15;
  const int pair = wave>>1, kh = wave&1;
  const int qb = pair*32;

  const int sl = t>>2, sc = t&3;
  const int skey = 32*(sl>>5) + 2*(sl&15) + ((sl>>4)&1);
  const bf16* Kb  = Kh + (size_t)bh*NT*DH + (size_t)skey*DH + sc*8;
  const bf16* VbT = VTg + ((size_t)(h*DH) + sl)*NSEQT + (size_t)b*NT + sc*8;

  // Q fragments for this wave's 32 q-rows (two 16-row subtiles)
  bf16x8 qf[2][2];
  #pragma unroll
  for (int mt=0; mt<2; mt++){
    const bf16* Qb = Qh + ((size_t)bh*NQ + q0 + qb + mt*16 + mr)*DH;
    qf[mt][0] = *(const bf16x8*)(Qb + qq*8);
    qf[mt][1] = *(const bf16x8*)(Qb + 32 + qq*8);
  }

  f32x4 o[2][4] = {};
  float l[2][4] = {};
  unsigned int* Pw = &Ps[wave][0];

  // prefetch tile 0 into buffer 0
  {
    bf16* bp = &KV[0][0];
    gll16(Kb,        bp + t*8);
    gll16(Kb + 32,   bp + 2048 + t*8);
    gll16(VbT,       bp + 4096 + t*8);
    gll16(VbT + 32,  bp + 6144 + t*8);
  }

  for (int it = 0; it < NT/64; it++) {
    __syncthreads();
    if (it + 1 < NT/64) {
      int kt = (it+1)*64;
      bf16* bp = &KV[(it+1)&1][0];
      gll16(Kb  + (size_t)kt*DH,      bp + t*8);
      gll16(Kb  + (size_t)kt*DH + 32, bp + 2048 + t*8);
      gll16(VbT + kt,                 bp + 4096 + t*8);
      gll16(VbT + kt + 32,            bp + 6144 + t*8);
    }
    const bf16* cbuf = &KV[it&1][0];

    // K fragments: this wave's key half, 2 subtiles of 16 keys
    bf16x8 kf[2][2];
    #pragma unroll
    for (int g=0; g<2; g++){
      kf[g][0] = *(const bf16x8*)(cbuf + (32*kh + 16*g + mr)*32 + qq*8);
      kf[g][1] = *(const bf16x8*)(cbuf + 2048 + (32*kh + 16*g + mr)*32 + qq*8);
    }
    f32x4 s[2][2];
    #pragma unroll
    for (int mt=0; mt<2; mt++)
      #pragma unroll
      for (int g=0; g<2; g++){
        f32x4 z = {};
        z = __builtin_amdgcn_mfma_f32_16x16x32_bf16(qf[mt][0], kf[g][0], z, 0,0,0);
        z = __builtin_amdgcn_mfma_f32_16x16x32_bf16(qf[mt][1], kf[g][1], z, 0,0,0);
        s[mt][g] = z;
      }
    // V fragments: this wave's key-half panel
    bf16x8 vf[4];
    #pragma unroll
    for (int n2=0; n2<4; n2++)
      vf[n2] = *(const bf16x8*)(cbuf + 4096 + kh*2048 + (n2*16+mr)*32 + qq*8);

    // exp2 + pack pair (keys 2mr, 2mr+1 of the half) -> one word per q-row
    #pragma unroll
    for (int mt=0; mt<2; mt++)
      #pragma unroll
      for (int r=0; r<4; r++){
        float e0 = __builtin_amdgcn_exp2f(s[mt][0][r]);
        float e1 = __builtin_amdgcn_exp2f(s[mt][1][r]);
        l[mt][r] += e0 + e1;
        unsigned a0 = __float_as_uint(e0) + 0x8000u;
        unsigned a1 = __float_as_uint(e1) + 0x8000u;
        Pw[(mt*16 + qq*4 + r)*20 + mr] = __builtin_amdgcn_perm(a1, a0, 0x07060302u);
      }
    asm volatile("s_waitcnt lgkmcnt(0)" ::: "memory");
    bf16x8 pa[2];
    #pragma unroll
    for (int mt=0; mt<2; mt++)
      pa[mt] = *(const bf16x8*)(Pw + (mt*16+mr)*20 + qq*4);
    #pragma unroll
    for (int mt=0; mt<2; mt++)
      #pragma unroll
      for (int n2=0; n2<4; n2++)
        o[mt][n2] = __builtin_amdgcn_mfma_f32_16x16x32_bf16(pa[mt], vf[n2], o[mt][n2], 0,0,0);
  }

  // partial row sums over this wave's key half
  float lsum[2][4];
  #pragma unroll
  for (int mt=0; mt<2; mt++)
    #pragma unroll
    for (int r=0; r<4; r++){
      float v = l[mt][r];
      #pragma unroll
      for (int m=1;m<16;m<<=1) v += __shfl_xor(v, m, 16);
      lsum[mt][r] = v;
    }

  // cross-pair merge via LDS (waves kh=1 publish, kh=0 merge+normalize)
  __syncthreads();
  float* Of  = (float*)&KV[0][0];   // 64 rows x stride 68 f32 (17408 B)
  float* lsh = (float*)&Ps[0][0];   // 64 f32
  if (kh == 1) {
    #pragma unroll
    for (int mt=0; mt<2; mt++){
      #pragma unroll
      for (int n2=0; n2<4; n2++)
        #pragma unroll
        for (int r=0; r<4; r++)
          Of[(qb + mt*16 + qq*4 + r)*68 + n2*16 + mr] = o[mt][n2][r];
      if (mr == 0)
        #pragma unroll
        for (int r=0; r<4; r++)
          lsh[qb + mt*16 + qq*4 + r] = lsum[mt][r];
    }
  }
  __syncthreads();
  if (kh == 0) {
    #pragma unroll
    for (int mt=0; mt<2; mt++)
      #pragma unroll
      for (int r=0; r<4; r++){
        int row = qb + mt*16 + qq*4 + r;
        float rl = 1.0f / (lsum[mt][r] + lsh[row]);
        #pragma unroll
        for (int n2=0; n2<4; n2++){
          int idx = row*68 + n2*16 + mr;
          Of[idx] = (o[mt][n2][r] + Of[idx]) * rl;
        }
      }
  }
  __syncthreads();
  // vectorized store: each thread writes 16 bf16 of one row
  {
    int row = t>>2, seg = (t&3)*16;
    union { uint4 u[2]; bf16 hh[16]; } pkv;
    #pragma unroll
    for (int j=0;j<16;j++) pkv.hh[j] = __float2bfloat16(Of[row*68 + seg + j]);
    bf16* dst = Ctx + ((size_t)b*NQ + q0 + row)*DIM_ + h*DH + seg;
    *(uint4*)dst = pkv.u[0];
    *(uint4*)(dst+8) = pkv.u[1];
  }
}

// ------------------------------------------------------------------ launch
extern "C" void kernel_launch(void* const* d_in, const int* in_sizes, int n_in,
                              void* d_out, int out_size, void* d_ws, size_t ws_size,
                              hipStream_t stream)
{
  const float* query  = (const float*)d_in[0];
  const float* kv     = (const float*)d_in[1];
  const float* ln_q_g = (const float*)d_in[2];
  const float* ln_q_b = (const float*)d_in[3];
  const float* ln_kv_g= (const float*)d_in[4];
  const float* ln_kv_b= (const float*)d_in[5];
  const float* Wq = (const float*)d_in[6];
  const float* bq = (const float*)d_in[7];
  const float* Wk = (const float*)d_in[8];
  const float* bk = (const float*)d_in[9];
  const float* Wv = (const float*)d_in[10];
  const float* bv = (const float*)d_in[11];
  const float* Wo = (const float*)d_in[12];
  const float* bo = (const float*)d_in[13];
  float* out = (float*)d_out;

  char* ws = (char*)d_ws;
  size_t off = 0;
  auto take = [&](size_t bytes)->char* {
    char* p = ws + off; off += (bytes + 255) & ~(size_t)255; return p;
  };
  bf16* X    = (bf16*)take((size_t)B_*NT*DIM_*2);   // LN output (concat kv|q)
  bf16* Qhb  = (bf16*)take((size_t)B_*NQ*DIM_*2);   // head-major, pre-scaled
  bf16* Khb  = (bf16*)take((size_t)B_*NT*DIM_*2);   // head-major
  bf16* VTg  = (bf16*)take((size_t)DIM_*NSEQT*2);   // V^T [ch][b*NT+n]
  bf16* Ctx  = (bf16*)take((size_t)B_*NQ*DIM_*2);
  bf16* WtQ  = (bf16*)take((size_t)DIM_*DIM_*2);
  bf16* WtK  = (bf16*)take((size_t)DIM_*DIM_*2);
  bf16* WtV  = (bf16*)take((size_t)DIM_*DIM_*2);
  bf16* WtO  = (bf16*)take((size_t)DIM_*DIM_*2);

  prep2_kernel<<<3584, 256, 0, stream>>>(
      query, kv, ln_q_g, ln_q_b, ln_kv_g, ln_kv_b, X,
      Wq, Wk, Wv, Wo, WtQ, WtK, WtV, WtO);

  gemm_qkv3<<<1408, 256, 0, stream>>>(X, WtQ, WtK, WtV, bq, bk, bv,
                                      Qhb, Khb, VTg);

  attn6_kernel<<<512, 256, 0, stream>>>(Qhb, Khb, VTg, Ctx);

  gemm_o2<<<256, 256, 0, stream>>>(Ctx, WtO, bo, query, out);
}

// Round 9
// 234.757 us; speedup vs baseline: 1.3087x; 1.0181x over previous
//
#include <hip/hip_runtime.h>
#include <hip/hip_bf16.h>

#define B_    4
#define NQ    512
#define NKV   2048
#define NT    2560     // NKV + NQ
#define DIM_  1024
#define HEADS 16
#define DH    64
#define NSEQT 10240    // B_*NT
// SCALE * log2(e): attention uses raw exp2
#define SCALE_Q_L2E 0.18033688011112042f

typedef short bf16x8 __attribute__((ext_vector_type(8)));
typedef float f32x4  __attribute__((ext_vector_type(4)));
typedef __hip_bfloat16 bf16;

// async global->LDS, 16B per lane. Global side may be a per-lane gather;
// LDS side is wave-uniform base + lane*16.
__device__ inline void gll16(const bf16* g, bf16* l) {
  __builtin_amdgcn_global_load_lds(
      (const __attribute__((address_space(1))) unsigned int*)g,
      (__attribute__((address_space(3))) unsigned int*)l, 16, 0, 0);
}

#define VMCNT(n) asm volatile("s_waitcnt vmcnt(" #n ")" ::: "memory")
#define BAR() __builtin_amdgcn_s_barrier()

// ---------------------------------------------- fused LayerNorm + weight^T
// blocks [0, 2560): LN, one WAVE per row (4 rows/block, no syncthreads).
// blocks [2560, 3584): 4x trw 64x64 weight transpose tiles.
__global__ __launch_bounds__(256) void prep2_kernel(
    const float* __restrict__ query, const float* __restrict__ kv,
    const float* __restrict__ lgq, const float* __restrict__ lbq,
    const float* __restrict__ lgkv, const float* __restrict__ lbkv,
    bf16* __restrict__ X,
    const float* __restrict__ W0, const float* __restrict__ W1,
    const float* __restrict__ W2, const float* __restrict__ W3,
    bf16* __restrict__ T0, bf16* __restrict__ T1,
    bf16* __restrict__ T2, bf16* __restrict__ T3)
{
  __shared__ __align__(16) char psm[9216];
  const int t = threadIdx.x;
  const int blkid = blockIdx.x;
  if (blkid < 2560) {
    const int w = t>>6, l = t&63;
    const int R = blkid*4 + w;                 // global row in X
    int b = R / NT, r = R % NT;
    const float *src, *gp, *bp;
    if (r < NKV) { src = kv    + ((size_t)b*NKV + r)*DIM_;      gp = lgkv; bp = lbkv; }
    else         { src = query + ((size_t)b*NQ + (r-NKV))*DIM_; gp = lgq;  bp = lbq;  }
    float4 v[4];
    #pragma unroll
    for (int j=0;j<4;++j) v[j] = ((const float4*)src)[j*64 + l];
    float s = 0.f, s2 = 0.f;
    #pragma unroll
    for (int j=0;j<4;++j){
      s  += v[j].x+v[j].y+v[j].z+v[j].w;
      s2 += v[j].x*v[j].x+v[j].y*v[j].y+v[j].z*v[j].z+v[j].w*v[j].w;
    }
    #pragma unroll
    for (int m=1;m<64;m<<=1){ s += __shfl_xor(s,m,64); s2 += __shfl_xor(s2,m,64); }
    float mu = s*(1.0f/DIM_);
    float rs = rsqrtf(s2*(1.0f/DIM_) - mu*mu + 1e-5f);
    uint2* drow = (uint2*)(X + (size_t)R*DIM_);
    #pragma unroll
    for (int j=0;j<4;++j){
      float4 gg = ((const float4*)gp)[j*64 + l];
      float4 b4 = ((const float4*)bp)[j*64 + l];
      union { unsigned int u[2]; bf16 h[4]; } pk;
      pk.h[0] = __float2bfloat16((v[j].x-mu)*rs*gg.x + b4.x);
      pk.h[1] = __float2bfloat16((v[j].y-mu)*rs*gg.y + b4.y);
      pk.h[2] = __float2bfloat16((v[j].z-mu)*rs*gg.z + b4.z);
      pk.h[3] = __float2bfloat16((v[j].w-mu)*rs*gg.w + b4.w);
      drow[j*64 + l] = make_uint2(pk.u[0], pk.u[1]);
    }
  } else {
    int l = blkid - 2560;
    const float* W; bf16* Wt;
    switch (l>>8) {
      case 0: W=W0; Wt=T0; break;
      case 1: W=W1; Wt=T1; break;
      case 2: W=W2; Wt=T2; break;
      default: W=W3; Wt=T3; break;
    }
    int rem = l & 255;
    int k0 = (rem&15)*64, n0 = (rem>>4)*64;
    bf16* Ws = (bf16*)psm;            // 64 x 72
    int kr = t>>2, nseg = (t&3)*16;
    const float4* s4 = (const float4*)(W + (size_t)(k0+kr)*DIM_ + n0 + nseg);
    union { uint4 u[2]; bf16 h[16]; } pk;
    #pragma unroll
    for (int j=0;j<4;j++){
      float4 v = s4[j];
      pk.h[j*4+0]=__float2bfloat16(v.x); pk.h[j*4+1]=__float2bfloat16(v.y);
      pk.h[j*4+2]=__float2bfloat16(v.z); pk.h[j*4+3]=__float2bfloat16(v.w);
    }
    *(uint4*)(Ws + kr*72 + nseg)     = pk.u[0];
    *(uint4*)(Ws + kr*72 + nseg + 8) = pk.u[1];
    __syncthreads();
    int n = t&63, kseg = t>>6;
    union { uint4 u[2]; bf16 h[16]; } o;
    #pragma unroll
    for (int k=0;k<16;k++) o.h[k] = Ws[(kseg*16+k)*72 + n];
    bf16* dst = Wt + (size_t)(n0+n)*DIM_ + k0 + kseg*16;
    *(uint4*)dst = o.u[0];
    *(uint4*)(dst+8) = o.u[1];
  }
}

// ------------------------------------------------------------- GEMM core v2
// (round-3 proven) 128x128 tile, BK=64, 4 waves (2x2), double-buffered 64 KiB
// LDS, granule-XOR swizzle (conflict-free ds_read_b128), one vmcnt(0)+barrier
// per K-tile, stages issued at tile top; 2 blocks/CU.
__device__ __forceinline__ void gemm_core2(
    const bf16* __restrict__ A, const bf16* __restrict__ Bmat,
    const float* __restrict__ bias, const float* __restrict__ residual,
    void* __restrict__ outv, int rows_per_batch, int row_offset,
    int a_batch_stride_rows, int n_seq, float scale,
    int emode, int m0, int n0, char* smem)
{
  char* const sA = smem;             // 2 x 16384
  char* const sB = smem + 32768;     // 2 x 16384
  float* Ts = (float*)smem;          // epilogue: 32 rows x stride 132

  const int t = threadIdx.x;
  const int srow = t >> 3;                 // 0..31: row within 32-row chunk
  const int gsw  = (t & 7) ^ (srow & 7);   // pre-swizzled source granule
  const bf16* pA[4]; const bf16* pB[4];
  #pragma unroll
  for (int c = 0; c < 4; ++c) {
    int gm = m0 + c*32 + srow;
    int bi = gm / rows_per_batch;
    pA[c] = A + ((size_t)bi*a_batch_stride_rows + row_offset
                 + (gm - bi*rows_per_batch))*(size_t)DIM_ + gsw*8;
    pB[c] = Bmat + (size_t)(n0 + c*32 + srow)*(size_t)DIM_ + gsw*8;
  }
  const int toff = t*16;

  const int wave = t>>6, lane = t&63, qq = lane>>4, mr = lane&15;
  const int wm = (wave>>1)*64, wn = (wave&1)*64;
  const int xq0 = (( qq    ) ^ (mr&7)) << 4;
  const int xq1 = ((4 + qq ) ^ (mr&7)) << 4;

  f32x4 acc[4][4] = {};

  // prologue: stage tile 0 -> buffer 0
  #pragma unroll
  for (int c=0;c<4;++c) gll16(pA[c], (bf16*)(sA + c*4096 + toff));
  #pragma unroll
  for (int c=0;c<4;++c) gll16(pB[c], (bf16*)(sB + c*4096 + toff));
  VMCNT(0);
  BAR();

  for (int kt = 0; kt < 16; ++kt) {
    const int cb = (kt&1) << 14;
    const int nb = ((kt+1)&1) << 14;
    if (kt < 15) {
      const int ko = (kt+1)*64;
      #pragma unroll
      for (int c=0;c<4;++c) gll16(pA[c] + ko, (bf16*)(sA + nb + c*4096 + toff));
      #pragma unroll
      for (int c=0;c<4;++c) gll16(pB[c] + ko, (bf16*)(sB + nb + c*4096 + toff));
    }
    #pragma unroll
    for (int kh = 0; kh < 2; ++kh) {
      const int xq = kh ? xq1 : xq0;
      bf16x8 af[4], bfr[4];
      #pragma unroll
      for (int ms=0; ms<4; ++ms)
        af[ms]  = *(const bf16x8*)(sA + cb + (wm + ms*16 + mr)*128 + xq);
      #pragma unroll
      for (int ns=0; ns<4; ++ns)
        bfr[ns] = *(const bf16x8*)(sB + cb + (wn + ns*16 + mr)*128 + xq);
      __builtin_amdgcn_s_setprio(1);
      #pragma unroll
      for (int ms=0; ms<4; ++ms)
        #pragma unroll
        for (int ns=0; ns<4; ++ns)
          acc[ms][ns] = __builtin_amdgcn_mfma_f32_16x16x32_bf16(
              af[ms], bfr[ns], acc[ms][ns], 0,0,0);
      __builtin_amdgcn_s_setprio(0);
    }
    VMCNT(0);   // own-wave next-tile stages landed; barrier joins all waves
    BAR();
  }
  __syncthreads();

  // epilogue: 4 rounds of 32 rows through LDS
  const int lr = t>>3, cs = (t&7)*16;
  for (int R=0; R<4; R++){
    if ((wave>>1) == (R>>1)) {
      #pragma unroll
      for (int ms2=0; ms2<2; ms2++){
        int ms = (R&1)*2 + ms2;
        #pragma unroll
        for (int ns=0; ns<4; ns++){
          int col = wn + ns*16 + mr;
          #pragma unroll
          for (int r=0;r<4;r++)
            Ts[(ms2*16 + qq*4 + r)*132 + col] = acc[ms][ns][r];
        }
      }
    }
    __syncthreads();
    float v[16];
    #pragma unroll
    for (int j=0;j<4;j++){
      float4 f = *(const float4*)(Ts + lr*132 + cs + j*4);
      v[j*4+0]=f.x; v[j*4+1]=f.y; v[j*4+2]=f.z; v[j*4+3]=f.w;
    }
    int gr = m0 + R*32 + lr;
    int gc = n0 + cs;
    if (emode == 0) {
      float* out = (float*)outv;
      size_t base = (size_t)gr*DIM_ + gc;
      #pragma unroll
      for (int j=0;j<4;j++){
        float4 bv = *(const float4*)(bias + gc + j*4);
        float4 rv = *(const float4*)(residual + base + j*4);
        float4 o4;
        o4.x = v[j*4+0] + bv.x + rv.x;
        o4.y = v[j*4+1] + bv.y + rv.y;
        o4.z = v[j*4+2] + bv.z + rv.z;
        o4.w = v[j*4+3] + bv.w + rv.w;
        *(float4*)(out + base + j*4) = o4;
      }
    } else if (emode == 1) {
      int bb = gr / rows_per_batch;
      int n  = gr - bb*rows_per_batch;
      int hh = gc>>6, dh = gc&63;
      bf16* out = (bf16*)outv + ((size_t)(bb*HEADS + hh)*n_seq + n)*DH + dh;
      union { uint4 u[2]; bf16 h[16]; } pk;
      #pragma unroll
      for (int j=0;j<16;j++) pk.h[j] = __float2bfloat16((v[j] + bias[gc+j])*scale);
      *(uint4*)out     = pk.u[0];
      *(uint4*)(out+8) = pk.u[1];
    } else {
      float bc = bias[gr];
      bf16* out = (bf16*)outv + (size_t)gr*NSEQT + gc;
      union { uint4 u[2]; bf16 h[16]; } pk;
      #pragma unroll
      for (int j=0;j<16;j++) pk.h[j] = __float2bfloat16(v[j] + bc);
      *(uint4*)out     = pk.u[0];
      *(uint4*)(out+8) = pk.u[1];
    }
    __syncthreads();
  }
}

// -------------------------------------------- fused Q/K/V projection GEMMs
__global__ __launch_bounds__(256) void gemm_qkv3(
    const bf16* __restrict__ X,
    const bf16* __restrict__ WtQ, const bf16* __restrict__ WtK,
    const bf16* __restrict__ WtV,
    const float* __restrict__ bq, const float* __restrict__ bk,
    const float* __restrict__ bv,
    bf16* __restrict__ Qhb, bf16* __restrict__ Khb, bf16* __restrict__ VTg)
{
  __shared__ __align__(16) char smem[65536];
  const int blk = blockIdx.x;
  if (blk < 128) {
    gemm_core2(X, WtQ, bq, nullptr, Qhb, NQ, NKV, NT, NQ, SCALE_Q_L2E, 1,
               (blk&15)*128, (blk>>4)*128, smem);
  } else if (blk < 768) {
    int l = blk - 128;
    gemm_core2(X, WtK, bk, nullptr, Khb, NT, 0, NT, NT, 1.0f, 1,
               (l%80)*128, (l/80)*128, smem);
  } else {
    int l = blk - 768;
    gemm_core2(WtV, X, bv, nullptr, VTg, DIM_, 0, DIM_, NSEQT, 1.0f, 2,
               (l/80)*128, (l%80)*128, smem);
  }
}

// ------------------------------------------------ output projection GEMM
__global__ __launch_bounds__(256) void gemm_o(
    const bf16* __restrict__ Ctx, const bf16* __restrict__ WtO,
    const float* __restrict__ bo, const float* __restrict__ residual,
    float* __restrict__ out)
{
  __shared__ __align__(16) char smem[65536];
  const int blk = blockIdx.x;
  gemm_core2(Ctx, WtO, bo, residual, out, B_*NQ, 0, B_*NQ, NQ, 1.0f, 0,
             (blk&15)*128, (blk>>4)*128, smem);
}

// --------------------------------------------------------------- Attention
// attn9: 128 q-rows per block (2 q-tiles fused) -> KV traffic HALVED
// (336->168 MB through L2/L3; attn6 measured ~6.1 TB/s = BW-bound).
// 4 waves, each owns 32 q-rows x FULL 64 keys (no kh split):
//  - no cross-pair merge phase; row sum = 16-lane shuffle (complete);
//  - normalization fused into the epilogue publish.
// K staged key-interleaved exactly as attn6 (skey formula covers 64 rows);
// P rows = 36 words (two 16-word halves + pad) keeping pa reads 2-way.
// LDS: KV dbuf 32K + per-wave P 4x4608=18K = 50K; epilogue Of overlays.
// 256 blocks (64 bh x 4 q-tiles), same-bh blocks same XCD slot.
__global__ __launch_bounds__(256) void attn9_kernel(
    const bf16* __restrict__ Qh, const bf16* __restrict__ Kh,
    const bf16* __restrict__ VTg, bf16* __restrict__ Ctx)
{
  __shared__ __align__(16) char SM[51200];
  bf16* const KV0 = (bf16*)SM;                       // 2 x 8192 elements

  const int t = threadIdx.x, wave = t>>6, lane = t&63;
  const int qq = lane>>4, mr = lane&15;
  const int blk = blockIdx.x;
  const int bh = (blk&7)*8 + (blk>>5);      // same bh -> same blk%8 (XCD)
  const int q0 = ((blk>>3)&3)*128;
  const int b = bh>>4, h = bh&15;
  const int qb = wave*32;

  const int sl = t>>2, sc = t&3;
  const int skey = 32*(sl>>5) + 2*(sl&15) + ((sl>>4)&1);
  const bf16* Kb  = Kh + (size_t)bh*NT*DH + (size_t)skey*DH + sc*8;
  const bf16* VbT = VTg + ((size_t)(h*DH) + sl)*NSEQT + (size_t)b*NT + sc*8;

  // Q fragments for this wave's 32 q-rows (two 16-row subtiles)
  bf16x8 qf[2][2];
  #pragma unroll
  for (int mt=0; mt<2; mt++){
    const bf16* Qb = Qh + ((size_t)bh*NQ + q0 + qb + mt*16 + mr)*DH;
    qf[mt][0] = *(const bf16x8*)(Qb + qq*8);
    qf[mt][1] = *(const bf16x8*)(Qb + 32 + qq*8);
  }

  f32x4 o[2][4] = {};
  float l[2][4] = {};
  unsigned int* const Pw = (unsigned int*)(SM + 32768 + wave*4608);

  const int NIT = NT/64;   // 40

  // prefetch tile 0 into buffer 0
  {
    bf16* bp = KV0;
    gll16(Kb,        bp + t*8);
    gll16(Kb + 32,   bp + 2048 + t*8);
    gll16(VbT,       bp + 4096 + t*8);
    gll16(VbT + 32,  bp + 6144 + t*8);
  }

  for (int it = 0; it < NIT; it++) {
    __syncthreads();
    if (it + 1 < NIT) {
      int kt = (it+1)*64;
      bf16* bp = KV0 + ((it+1)&1)*8192;
      gll16(Kb  + (size_t)kt*DH,      bp + t*8);
      gll16(Kb  + (size_t)kt*DH + 32, bp + 2048 + t*8);
      gll16(VbT + kt,                 bp + 4096 + t*8);
      gll16(VbT + kt + 32,            bp + 6144 + t*8);
    }
    const bf16* cbuf = KV0 + (it&1)*8192;

    // QK^T over all 4 key-subtiles (stream K fragments)
    f32x4 s[2][4];
    __builtin_amdgcn_s_setprio(1);
    #pragma unroll
    for (int g=0; g<4; g++){
      bf16x8 k0 = *(const bf16x8*)(cbuf + (16*g + mr)*32 + qq*8);
      bf16x8 k1 = *(const bf16x8*)(cbuf + 2048 + (16*g + mr)*32 + qq*8);
      #pragma unroll
      for (int mt=0; mt<2; mt++){
        f32x4 z = {};
        z = __builtin_amdgcn_mfma_f32_16x16x32_bf16(qf[mt][0], k0, z, 0,0,0);
        z = __builtin_amdgcn_mfma_f32_16x16x32_bf16(qf[mt][1], k1, z, 0,0,0);
        s[mt][g] = z;
      }
    }
    __builtin_amdgcn_s_setprio(0);

    // V fragments: both key-halves
    bf16x8 vf[2][4];
    #pragma unroll
    for (int hh=0; hh<2; hh++)
      #pragma unroll
      for (int n2=0; n2<4; n2++)
        vf[hh][n2] = *(const bf16x8*)(cbuf + 4096 + hh*2048 + (n2*16+mr)*32 + qq*8);

    // exp2 + pack pairs: subtiles (2h, 2h+1) -> keys (32h+2mr, 32h+2mr+1)
    #pragma unroll
    for (int mt=0; mt<2; mt++)
      #pragma unroll
      for (int r=0; r<4; r++){
        float e0 = __builtin_amdgcn_exp2f(s[mt][0][r]);
        float e1 = __builtin_amdgcn_exp2f(s[mt][1][r]);
        float e2 = __builtin_amdgcn_exp2f(s[mt][2][r]);
        float e3 = __builtin_amdgcn_exp2f(s[mt][3][r]);
        l[mt][r] += (e0 + e1) + (e2 + e3);
        unsigned a0 = __float_as_uint(e0) + 0x8000u;
        unsigned a1 = __float_as_uint(e1) + 0x8000u;
        unsigned a2 = __float_as_uint(e2) + 0x8000u;
        unsigned a3 = __float_as_uint(e3) + 0x8000u;
        int prow = (mt*16 + qq*4 + r)*36;
        Pw[prow + mr]      = __builtin_amdgcn_perm(a1, a0, 0x07060302u);
        Pw[prow + 16 + mr] = __builtin_amdgcn_perm(a3, a2, 0x07060302u);
      }
    asm volatile("s_waitcnt lgkmcnt(0)" ::: "memory");
    bf16x8 pa[2][2];
    #pragma unroll
    for (int mt=0; mt<2; mt++)
      #pragma unroll
      for (int hh=0; hh<2; hh++)
        pa[mt][hh] = *(const bf16x8*)(Pw + (mt*16+mr)*36 + hh*16 + qq*4);
    __builtin_amdgcn_s_setprio(1);
    #pragma unroll
    for (int mt=0; mt<2; mt++)
      #pragma unroll
      for (int n2=0; n2<4; n2++){
        o[mt][n2] = __builtin_amdgcn_mfma_f32_16x16x32_bf16(pa[mt][0], vf[0][n2], o[mt][n2], 0,0,0);
        o[mt][n2] = __builtin_amdgcn_mfma_f32_16x16x32_bf16(pa[mt][1], vf[1][n2], o[mt][n2], 0,0,0);
      }
    __builtin_amdgcn_s_setprio(0);
  }

  // full row sums (all 64 keys were in-wave) -> 16-lane shuffle
  float lsum[2][4];
  #pragma unroll
  for (int mt=0; mt<2; mt++)
    #pragma unroll
    for (int r=0; r<4; r++){
      float v = l[mt][r];
      #pragma unroll
      for (int m=1;m<16;m<<=1) v += __shfl_xor(v, m, 16);
      lsum[mt][r] = v;
    }

  // epilogue: normalized publish to LDS, then vectorized store
  __syncthreads();
  float* Of = (float*)SM;           // 128 rows x stride 68 f32 (34816 B)
  #pragma unroll
  for (int mt=0; mt<2; mt++)
    #pragma unroll
    for (int r=0; r<4; r++){
      float rl = 1.0f / lsum[mt][r];
      #pragma unroll
      for (int n2=0; n2<4; n2++)
        Of[(qb + mt*16 + qq*4 + r)*68 + n2*16 + mr] = o[mt][n2][r] * rl;
    }
  __syncthreads();
  {
    int row = t>>1, seg = (t&1)*32;
    union { uint4 u[4]; bf16 hh[32]; } pkv;
    #pragma unroll
    for (int j=0;j<32;j++) pkv.hh[j] = __float2bfloat16(Of[row*68 + seg + j]);
    bf16* dst = Ctx + ((size_t)b*NQ + q0 + row)*DIM_ + h*DH + seg;
    uint4* d = (uint4*)dst;
    d[0] = pkv.u[0]; d[1] = pkv.u[1]; d[2] = pkv.u[2]; d[3] = pkv.u[3];
  }
}

// ------------------------------------------------------------------ launch
extern "C" void kernel_launch(void* const* d_in, const int* in_sizes, int n_in,
                              void* d_out, int out_size, void* d_ws, size_t ws_size,
                              hipStream_t stream)
{
  const float* query  = (const float*)d_in[0];
  const float* kv     = (const float*)d_in[1];
  const float* ln_q_g = (const float*)d_in[2];
  const float* ln_q_b = (const float*)d_in[3];
  const float* ln_kv_g= (const float*)d_in[4];
  const float* ln_kv_b= (const float*)d_in[5];
  const float* Wq = (const float*)d_in[6];
  const float* bq = (const float*)d_in[7];
  const float* Wk = (const float*)d_in[8];
  const float* bk = (const float*)d_in[9];
  const float* Wv = (const float*)d_in[10];
  const float* bv = (const float*)d_in[11];
  const float* Wo = (const float*)d_in[12];
  const float* bo = (const float*)d_in[13];
  float* out = (float*)d_out;

  char* ws = (char*)d_ws;
  size_t off = 0;
  auto take = [&](size_t bytes)->char* {
    char* p = ws + off; off += (bytes + 255) & ~(size_t)255; return p;
  };
  bf16* X    = (bf16*)take((size_t)B_*NT*DIM_*2);   // LN output (concat kv|q)
  bf16* Qhb  = (bf16*)take((size_t)B_*NQ*DIM_*2);   // head-major, pre-scaled
  bf16* Khb  = (bf16*)take((size_t)B_*NT*DIM_*2);   // head-major
  bf16* VTg  = (bf16*)take((size_t)DIM_*NSEQT*2);   // V^T [ch][b*NT+n]
  bf16* Ctx  = (bf16*)take((size_t)B_*NQ*DIM_*2);
  bf16* WtQ  = (bf16*)take((size_t)DIM_*DIM_*2);
  bf16* WtK  = (bf16*)take((size_t)DIM_*DIM_*2);
  bf16* WtV  = (bf16*)take((size_t)DIM_*DIM_*2);
  bf16* WtO  = (bf16*)take((size_t)DIM_*DIM_*2);

  prep2_kernel<<<3584, 256, 0, stream>>>(
      query, kv, ln_q_g, ln_q_b, ln_kv_g, ln_kv_b, X,
      Wq, Wk, Wv, Wo, WtQ, WtK, WtV, WtO);

  gemm_qkv3<<<1408, 256, 0, stream>>>(X, WtQ, WtK, WtV, bq, bk, bv,
                                      Qhb, Khb, VTg);

  attn9_kernel<<<256, 256, 0, stream>>>(Qhb, Khb, VTg, Ctx);

  gemm_o<<<128, 256, 0, stream>>>(Ctx, WtO, bo, query, out);
}